// Round 1
// baseline (610.454 us; speedup 1.0000x reference)
//
#include <hip/hip_runtime.h>

// ---------------- problem constants ----------------
constexpr int CB = 64;          // batch
constexpr int CHH = 14, CWW = 14;
constexpr int CN = 196;         // CHH*CWW
constexpr int CC = 1024;        // channels
constexpr int CROWS = CB * CN;  // 12544
constexpr int CKW = 8;          // rfft bins along W

// twiddles: cos/sin(2*pi*m/14), m=0..13
constexpr float C14[14] = {
  1.0f, 0.9009688679024191f, 0.6234898018587336f, 0.2225209339563144f,
  -0.2225209339563144f, -0.6234898018587336f, -0.9009688679024191f, -1.0f,
  -0.9009688679024191f, -0.6234898018587336f, -0.2225209339563144f,
  0.2225209339563144f, 0.6234898018587336f, 0.9009688679024191f };
constexpr float S14[14] = {
  0.0f, 0.4338837391175581f, 0.7818314824680298f, 0.9749279121818236f,
  0.9749279121818236f, 0.7818314824680298f, 0.4338837391175581f, 0.0f,
  -0.4338837391175581f, -0.7818314824680298f, -0.9749279121818236f,
  -0.9749279121818236f, -0.7818314824680298f, -0.4338837391175581f };

typedef __attribute__((ext_vector_type(8))) short bf16x8;
typedef __attribute__((ext_vector_type(4))) float f32x4;

__device__ __forceinline__ unsigned short f2bf(float f) {
  unsigned u = __builtin_bit_cast(unsigned, f);
  u += 0x7FFFu + ((u >> 16) & 1u);   // RNE
  return (unsigned short)(u >> 16);
}
__device__ __forceinline__ float bf2f(unsigned short h) {
  return __builtin_bit_cast(float, (unsigned)h << 16);
}

__device__ __forceinline__ void gload_lds16(const void* g, void* l) {
  __builtin_amdgcn_global_load_lds(
      (const __attribute__((address_space(1))) void*)g,
      (__attribute__((address_space(3))) void*)l, 16, 0, 0);
}

// ---------------- LayerNorm over C=1024 (one block per row) ----------------
template<int OUTBF>
__global__ __launch_bounds__(256)
void ln_kernel(const float* __restrict__ in, const float* __restrict__ gam,
               const float* __restrict__ bet, float* __restrict__ outf,
               unsigned short* __restrict__ outb)
{
  const int row = blockIdx.x;
  const int t = threadIdx.x;
  const float4 v = *(const float4*)(in + (size_t)row * CC + t * 4);
  float s  = v.x + v.y + v.z + v.w;
  float s2 = v.x*v.x + v.y*v.y + v.z*v.z + v.w*v.w;
  #pragma unroll
  for (int o = 32; o > 0; o >>= 1) { s += __shfl_down(s, o); s2 += __shfl_down(s2, o); }
  __shared__ float red[8];
  const int wid = t >> 6, lane = t & 63;
  if (lane == 0) { red[wid] = s; red[4 + wid] = s2; }
  __syncthreads();
  s  = red[0] + red[1] + red[2] + red[3];
  s2 = red[4] + red[5] + red[6] + red[7];
  const float mean = s * (1.0f / CC);
  const float var  = s2 * (1.0f / CC) - mean * mean;
  const float r = rsqrtf(var + 1e-5f);
  const float4 g4 = *(const float4*)(gam + t * 4);
  const float4 b4 = *(const float4*)(bet + t * 4);
  const float o0 = (v.x - mean) * r * g4.x + b4.x;
  const float o1 = (v.y - mean) * r * g4.y + b4.y;
  const float o2 = (v.z - mean) * r * g4.z + b4.z;
  const float o3 = (v.w - mean) * r * g4.w + b4.w;
  if (OUTBF) {
    ushort4 p; p.x = f2bf(o0); p.y = f2bf(o1); p.z = f2bf(o2); p.w = f2bf(o3);
    *(ushort4*)(outb + (size_t)row * CC + t * 4) = p;
  } else {
    *(float4*)(outf + (size_t)row * CC + t * 4) = make_float4(o0, o1, o2, o3);
  }
}

// ---------------- rfft along W: [B,H,W,C] real -> [B,H,8,C] complex ----------------
__global__ __launch_bounds__(256)
void fft_w_fwd(const float* __restrict__ y, float* __restrict__ Ar, float* __restrict__ Ai)
{
  const int t = threadIdx.x;
  const int bid = blockIdx.x;      // ((b*14)+h)*4 + cc
  const int cc = bid & 3;
  const int tmp = bid >> 2;
  const int h = tmp % 14;
  const int b = tmp / 14;
  const int c = cc * 256 + t;
  const size_t base = ((size_t)b * CN + (size_t)h * CWW) * CC + c;
  float v[14];
  #pragma unroll
  for (int w = 0; w < 14; w++) v[w] = y[base + (size_t)w * CC];
  const size_t obase = (((size_t)b * CHH + h) * CKW) * CC + c;
  #pragma unroll
  for (int kw = 0; kw < 8; kw++) {
    float sr = 0.f, si = 0.f;
    #pragma unroll
    for (int w = 0; w < 14; w++) {
      const int m = (w * kw) % 14;
      sr += v[w] * C14[m];
      si -= v[w] * S14[m];
    }
    Ar[obase + (size_t)kw * CC] = sr;
    Ai[obase + (size_t)kw * CC] = si;
  }
}

// ---------------- fft along H + complex filter + ifft along H ----------------
__global__ __launch_bounds__(256)
void fft_h_filt(const float* __restrict__ Ar, const float* __restrict__ Ai,
                const float* __restrict__ cw, float* __restrict__ Br, float* __restrict__ Bi)
{
  const int t = threadIdx.x;
  const int bid = blockIdx.x;      // ((b*8)+kw)*4 + cc
  const int cc = bid & 3;
  const int tmp = bid >> 2;
  const int kw = tmp & 7;
  const int b = tmp >> 3;
  const int c = cc * 256 + t;
  const size_t base = (((size_t)b * CHH) * CKW + kw) * CC + c;   // h stride = CKW*CC
  float ar[14], ai[14];
  #pragma unroll
  for (int h = 0; h < 14; h++) {
    ar[h] = Ar[base + (size_t)h * (CKW * CC)];
    ai[h] = Ai[base + (size_t)h * (CKW * CC)];
  }
  float fr[14], fi[14];
  #pragma unroll
  for (int kh = 0; kh < 14; kh++) {
    float yr = 0.f, yi = 0.f;
    #pragma unroll
    for (int h = 0; h < 14; h++) {
      const int m = (h * kh) % 14;
      yr += ar[h] * C14[m] + ai[h] * S14[m];
      yi += ai[h] * C14[m] - ar[h] * S14[m];
    }
    const size_t widx = (((size_t)kh * CKW + kw) * CC + c) * 2;
    const float wr = cw[widx], wi = cw[widx + 1];
    fr[kh] = yr * wr - yi * wi;
    fi[kh] = yr * wi + yi * wr;
  }
  #pragma unroll
  for (int h = 0; h < 14; h++) {
    float sr = 0.f, si = 0.f;
    #pragma unroll
    for (int kh = 0; kh < 14; kh++) {
      const int m = (h * kh) % 14;
      sr += fr[kh] * C14[m] - fi[kh] * S14[m];
      si += fr[kh] * S14[m] + fi[kh] * C14[m];
    }
    Br[base + (size_t)h * (CKW * CC)] = sr;
    Bi[base + (size_t)h * (CKW * CC)] = si;
  }
}

// ---------------- irfft along W (c2r: imag of DC/Nyquist ignored) ----------------
__global__ __launch_bounds__(256)
void fft_w_inv(const float* __restrict__ Br, const float* __restrict__ Bi, float* __restrict__ y2)
{
  const int t = threadIdx.x;
  const int bid = blockIdx.x;
  const int cc = bid & 3;
  const int tmp = bid >> 2;
  const int h = tmp % 14;
  const int b = tmp / 14;
  const int c = cc * 256 + t;
  const size_t ibase = (((size_t)b * CHH + h) * CKW) * CC + c;
  float br[8], bi[8];
  #pragma unroll
  for (int k = 0; k < 8; k++) {
    br[k] = Br[ibase + (size_t)k * CC];
    bi[k] = Bi[ibase + (size_t)k * CC];
  }
  const size_t obase = ((size_t)b * CN + (size_t)h * CWW) * CC + c;
  #pragma unroll
  for (int w = 0; w < 14; w++) {
    float s = br[0] + ((w & 1) ? -br[7] : br[7]);
    #pragma unroll
    for (int k = 1; k < 7; k++) {
      const int m = (w * k) % 14;
      s += 2.0f * (br[k] * C14[m] - bi[k] * S14[m]);
    }
    y2[obase + (size_t)w * CC] = s * (1.0f / 196.0f);   // ortho fwd*inv = 1/196
  }
}

// ---------------- transpose fp32 [R,Cc] -> bf16 [Cc,R] ----------------
__global__ __launch_bounds__(256)
void transpose_f32_bf16(const float* __restrict__ in, unsigned short* __restrict__ out,
                        int R, int Ccols)
{
  __shared__ float tile[32][33];
  const int tx = threadIdx.x & 31;
  const int ty = threadIdx.x >> 5;     // 0..7
  const int cb = blockIdx.x * 32;
  const int rb = blockIdx.y * 32;
  #pragma unroll
  for (int i = 0; i < 32; i += 8)
    tile[ty + i][tx] = in[(size_t)(rb + ty + i) * Ccols + cb + tx];
  __syncthreads();
  #pragma unroll
  for (int i = 0; i < 32; i += 8)
    out[(size_t)(cb + ty + i) * R + rb + tx] = f2bf(tile[tx][ty + i]);
}

// ---------------- bf16 GEMM, m97 structure: C[M,N] = A[M,K] * BT[N,K]^T ----------------
// epilogue: + bias, optional exact GELU, bf16 store
__global__ __launch_bounds__(256)
void gemm_bt(const unsigned short* __restrict__ A, const unsigned short* __restrict__ BT,
             const float* __restrict__ bias, unsigned short* __restrict__ C,
             int M, int N, int K, int do_gelu)
{
  __shared__ __align__(16) short sA[128 * 32];
  __shared__ __align__(16) short sB[128 * 32];
  const int t = threadIdx.x;
  const int wid = t >> 6, lane = t & 63;
  const int brow = blockIdx.y * 128, bcol = blockIdx.x * 128;
  const int wm = wid >> 1, wn = wid & 1;      // 2x2 waves, 64x64 each
  f32x4 acc[4][4] = {};
  const int srow = t >> 2;                     // 0..63
  const int skc  = (t & 3) * 8;                // 0,8,16,24
  const size_t aoff0 = (size_t)(brow + srow) * K + skc;
  const size_t aoff1 = (size_t)(brow + srow + 64) * K + skc;
  const size_t boff0 = (size_t)(bcol + srow) * K + skc;
  const size_t boff1 = (size_t)(bcol + srow + 64) * K + skc;
  short* lA0 = &sA[t * 8];  short* lA1 = &sA[t * 8 + 64 * 32];
  short* lB0 = &sB[t * 8];  short* lB1 = &sB[t * 8 + 64 * 32];
  const int lrow = lane & 15, lk = (lane >> 4) * 8;

  for (int k0 = 0; k0 < K; k0 += 32) {
    gload_lds16(A + aoff0 + k0, lA0);
    gload_lds16(A + aoff1 + k0, lA1);
    gload_lds16(BT + boff0 + k0, lB0);
    gload_lds16(BT + boff1 + k0, lB1);
    asm volatile("s_waitcnt vmcnt(0)" ::: "memory");
    __syncthreads();
    bf16x8 af[4], bfr[4];
    #pragma unroll
    for (int m = 0; m < 4; m++)
      af[m] = *(const bf16x8*)&sA[(wm * 64 + m * 16 + lrow) * 32 + lk];
    #pragma unroll
    for (int n = 0; n < 4; n++)
      bfr[n] = *(const bf16x8*)&sB[(wn * 64 + n * 16 + lrow) * 32 + lk];
    #pragma unroll
    for (int m = 0; m < 4; m++)
      #pragma unroll
      for (int n = 0; n < 4; n++)
        acc[m][n] = __builtin_amdgcn_mfma_f32_16x16x32_bf16(af[m], bfr[n], acc[m][n], 0, 0, 0);
    __syncthreads();
  }

  const int rrow = (lane >> 4) * 4;
  #pragma unroll
  for (int m = 0; m < 4; m++) {
    #pragma unroll
    for (int n = 0; n < 4; n++) {
      const int ccol = bcol + wn * 64 + n * 16 + lrow;
      const float bb = bias[ccol];
      #pragma unroll
      for (int j = 0; j < 4; j++) {
        const int r = brow + wm * 64 + m * 16 + rrow + j;
        float v = acc[m][n][j] + bb;
        if (do_gelu) v = 0.5f * v * (1.0f + erff(v * 0.70710678118654752f));
        C[(size_t)r * N + ccol] = f2bf(v);
      }
    }
  }
}

// ---------------- FEM: 3 blockwise instance-norm gates fused + residual ----------------
__device__ __forceinline__ void fem_block(unsigned short* col, int t,
                                          int h0, int nh, int w0, int nw)
{
  float s = 0.f, s2 = 0.f;
  for (int ih = 0; ih < nh; ih++)
    for (int iw = 0; iw < nw; iw++) {
      const float v = bf2f(col[((h0 + ih) * 14 + w0 + iw) * 128 + t]);
      s += v; s2 += v * v;
    }
  const float inv = 1.0f / (float)(nh * nw);
  const float m = s * inv;
  const float var = s2 * inv - m * m;
  const float r = rsqrtf(var + 1e-5f);
  for (int ih = 0; ih < nh; ih++)
    for (int iw = 0; iw < nw; iw++) {
      const int idx = ((h0 + ih) * 14 + w0 + iw) * 128 + t;
      const float v = bf2f(col[idx]);
      const float a = 1.0f / (1.0f + __expf(-(v - m) * r));
      col[idx] = f2bf(0.5f * v * (1.0f + a));
    }
}

__global__ __launch_bounds__(128)
void fem_kernel(const unsigned short* __restrict__ z, const float* __restrict__ x,
                float* __restrict__ out)
{
  __shared__ unsigned short buf[CN * 128];   // 50,176 B; thread-private columns
  const int t = threadIdx.x;
  const int b = blockIdx.x >> 3;
  const int cc = blockIdx.x & 7;
  const int c = cc * 128 + t;
  const size_t base = (size_t)b * CN * CC + c;
  #pragma unroll 4
  for (int n = 0; n < CN; n++) buf[n * 128 + t] = z[base + (size_t)n * CC];
  // s = 3: 5x5 blocks, row/col starts {0,3,6,9,12}, lens {3,3,3,3,2}
  const int st3[5] = {0, 3, 6, 9, 12};
  const int ln3[5] = {3, 3, 3, 3, 2};
  for (int i = 0; i < 5; i++)
    for (int j = 0; j < 5; j++)
      fem_block(buf, t, st3[i], ln3[i], st3[j], ln3[j]);
  // s = 7: 2x2 blocks of 7x7
  for (int i = 0; i < 2; i++)
    for (int j = 0; j < 2; j++)
      fem_block(buf, t, i * 7, 7, j * 7, 7);
  // s = 14: whole field
  fem_block(buf, t, 0, 14, 0, 14);
  #pragma unroll 4
  for (int n = 0; n < CN; n++)
    out[base + (size_t)n * CC] = x[base + (size_t)n * CC] + bf2f(buf[n * 128 + t]);
}

// ---------------- launch ----------------
extern "C" void kernel_launch(void* const* d_in, const int* in_sizes, int n_in,
                              void* d_out, int out_size, void* d_ws, size_t ws_size,
                              hipStream_t stream) {
  const float* x     = (const float*)d_in[0];
  const float* ln1_g = (const float*)d_in[1];
  const float* ln1_b = (const float*)d_in[2];
  const float* cw    = (const float*)d_in[3];
  const float* ln2_g = (const float*)d_in[4];
  const float* ln2_b = (const float*)d_in[5];
  const float* fc1_w = (const float*)d_in[6];
  const float* fc1_b = (const float*)d_in[7];
  const float* fc2_w = (const float*)d_in[8];
  const float* fc2_b = (const float*)d_in[9];
  float* out = (float*)d_out;
  char* ws = (char*)d_ws;

  // arena (total 161.5 MB); d_out doubles as fp32 scratch for y1/y2
  const size_t SZ_A = (size_t)CB * CHH * CKW * CC * 4;       // 29,360,128 B
  float* Ar = (float*)(ws);
  float* Ai = (float*)(ws + SZ_A);
  float* Br = (float*)(ws + 2 * SZ_A);
  float* Bi = (float*)(ws + 3 * SZ_A);
  unsigned short* A1   = (unsigned short*)(ws);                        // after FFT done
  unsigned short* W1T  = (unsigned short*)(ws + SZ_A);                 // [4096,1024] bf16
  unsigned short* W2T  = (unsigned short*)(ws + SZ_A + (size_t)4096 * 1024 * 2); // [1024,4096]
  unsigned short* Hmid = (unsigned short*)(ws + 2 * SZ_A);             // [12544,4096] bf16
  unsigned short* Z    = (unsigned short*)(ws);                        // [12544,1024] bf16

  // 1. LN1: x -> y1 (in d_out)
  ln_kernel<0><<<CROWS, 256, 0, stream>>>(x, ln1_g, ln1_b, out, nullptr);
  // 2. rfft along W
  fft_w_fwd<<<CB * CHH * 4, 256, 0, stream>>>(out, Ar, Ai);
  // 3. fft along H + filter + ifft along H
  fft_h_filt<<<CB * CKW * 4, 256, 0, stream>>>(Ar, Ai, cw, Br, Bi);
  // 4. irfft along W -> y2 (in d_out)
  fft_w_inv<<<CB * CHH * 4, 256, 0, stream>>>(Br, Bi, out);
  // 5. LN2 -> bf16 A1
  ln_kernel<1><<<CROWS, 256, 0, stream>>>(out, ln2_g, ln2_b, nullptr, A1);
  // 6. weight prep (FFT intermediates dead)
  transpose_f32_bf16<<<dim3(4096 / 32, 1024 / 32), 256, 0, stream>>>(fc1_w, W1T, 1024, 4096);
  transpose_f32_bf16<<<dim3(1024 / 32, 4096 / 32), 256, 0, stream>>>(fc2_w, W2T, 4096, 1024);
  // 7. GEMM1 + bias + exact GELU -> Hmid bf16
  gemm_bt<<<dim3(4096 / 128, CROWS / 128), 256, 0, stream>>>(A1, W1T, fc1_b, Hmid,
                                                             CROWS, 4096, 1024, 1);
  // 8. GEMM2 + bias -> Z bf16
  gemm_bt<<<dim3(1024 / 128, CROWS / 128), 256, 0, stream>>>(Hmid, W2T, fc2_b, Z,
                                                             CROWS, 1024, 4096, 0);
  // 9. FEM x3 fused + residual -> out
  fem_kernel<<<CB * 8, 128, 0, stream>>>(Z, x, out);
}

// Round 2
// 518.186 us; speedup vs baseline: 1.1781x; 1.1781x over previous
//
#include <hip/hip_runtime.h>

// ---------------- problem constants ----------------
constexpr int CB = 64;          // batch
constexpr int CHH = 14, CWW = 14;
constexpr int CN = 196;         // CHH*CWW
constexpr int CC = 1024;        // channels
constexpr int CROWS = CB * CN;  // 12544
constexpr int CKW = 8;          // rfft bins along W

// twiddles: cos/sin(2*pi*m/14), m=0..13
constexpr float C14[14] = {
  1.0f, 0.9009688679024191f, 0.6234898018587336f, 0.2225209339563144f,
  -0.2225209339563144f, -0.6234898018587336f, -0.9009688679024191f, -1.0f,
  -0.9009688679024191f, -0.6234898018587336f, -0.2225209339563144f,
  0.2225209339563144f, 0.6234898018587336f, 0.9009688679024191f };
constexpr float S14[14] = {
  0.0f, 0.4338837391175581f, 0.7818314824680298f, 0.9749279121818236f,
  0.9749279121818236f, 0.7818314824680298f, 0.4338837391175581f, 0.0f,
  -0.4338837391175581f, -0.7818314824680298f, -0.9749279121818236f,
  -0.9749279121818236f, -0.7818314824680298f, -0.4338837391175581f };

typedef __attribute__((ext_vector_type(8))) short bf16x8;
typedef __attribute__((ext_vector_type(4))) float f32x4;

__device__ __forceinline__ unsigned short f2bf(float f) {
  unsigned u = __builtin_bit_cast(unsigned, f);
  u += 0x7FFFu + ((u >> 16) & 1u);   // RNE
  return (unsigned short)(u >> 16);
}
__device__ __forceinline__ float bf2f(unsigned short h) {
  return __builtin_bit_cast(float, (unsigned)h << 16);
}

__device__ __forceinline__ void gload_lds16(const void* g, void* l) {
  __builtin_amdgcn_global_load_lds(
      (const __attribute__((address_space(1))) void*)g,
      (__attribute__((address_space(3))) void*)l, 16, 0, 0);
}

#define WAITV(N) asm volatile("s_waitcnt vmcnt(" #N ")" ::: "memory")

// ---------------- LayerNorm over C=1024 (one block per row) ----------------
template<int OUTBF>
__global__ __launch_bounds__(256)
void ln_kernel(const float* __restrict__ in, const float* __restrict__ gam,
               const float* __restrict__ bet, float* __restrict__ outf,
               unsigned short* __restrict__ outb)
{
  const int row = blockIdx.x;
  const int t = threadIdx.x;
  const float4 v = *(const float4*)(in + (size_t)row * CC + t * 4);
  float s  = v.x + v.y + v.z + v.w;
  float s2 = v.x*v.x + v.y*v.y + v.z*v.z + v.w*v.w;
  #pragma unroll
  for (int o = 32; o > 0; o >>= 1) { s += __shfl_down(s, o); s2 += __shfl_down(s2, o); }
  __shared__ float red[8];
  const int wid = t >> 6, lane = t & 63;
  if (lane == 0) { red[wid] = s; red[4 + wid] = s2; }
  __syncthreads();
  s  = red[0] + red[1] + red[2] + red[3];
  s2 = red[4] + red[5] + red[6] + red[7];
  const float mean = s * (1.0f / CC);
  const float var  = s2 * (1.0f / CC) - mean * mean;
  const float r = rsqrtf(var + 1e-5f);
  const float4 g4 = *(const float4*)(gam + t * 4);
  const float4 b4 = *(const float4*)(bet + t * 4);
  const float o0 = (v.x - mean) * r * g4.x + b4.x;
  const float o1 = (v.y - mean) * r * g4.y + b4.y;
  const float o2 = (v.z - mean) * r * g4.z + b4.z;
  const float o3 = (v.w - mean) * r * g4.w + b4.w;
  if (OUTBF) {
    ushort4 p; p.x = f2bf(o0); p.y = f2bf(o1); p.z = f2bf(o2); p.w = f2bf(o3);
    *(ushort4*)(outb + (size_t)row * CC + t * 4) = p;
  } else {
    *(float4*)(outf + (size_t)row * CC + t * 4) = make_float4(o0, o1, o2, o3);
  }
}

// ---------------- rfft along W: [B,H,W,C] real -> [B,H,8,C] complex ----------------
__global__ __launch_bounds__(256)
void fft_w_fwd(const float* __restrict__ y, float* __restrict__ Ar, float* __restrict__ Ai)
{
  const int t = threadIdx.x;
  const int bid = blockIdx.x;      // ((b*14)+h)*4 + cc
  const int cc = bid & 3;
  const int tmp = bid >> 2;
  const int h = tmp % 14;
  const int b = tmp / 14;
  const int c = cc * 256 + t;
  const size_t base = ((size_t)b * CN + (size_t)h * CWW) * CC + c;
  float v[14];
  #pragma unroll
  for (int w = 0; w < 14; w++) v[w] = y[base + (size_t)w * CC];
  const size_t obase = (((size_t)b * CHH + h) * CKW) * CC + c;
  #pragma unroll
  for (int kw = 0; kw < 8; kw++) {
    float sr = 0.f, si = 0.f;
    #pragma unroll
    for (int w = 0; w < 14; w++) {
      const int m = (w * kw) % 14;
      sr += v[w] * C14[m];
      si -= v[w] * S14[m];
    }
    Ar[obase + (size_t)kw * CC] = sr;
    Ai[obase + (size_t)kw * CC] = si;
  }
}

// ---------------- fft along H + complex filter + ifft along H ----------------
__global__ __launch_bounds__(256)
void fft_h_filt(const float* __restrict__ Ar, const float* __restrict__ Ai,
                const float* __restrict__ cw, float* __restrict__ Br, float* __restrict__ Bi)
{
  const int t = threadIdx.x;
  const int bid = blockIdx.x;      // ((b*8)+kw)*4 + cc
  const int cc = bid & 3;
  const int tmp = bid >> 2;
  const int kw = tmp & 7;
  const int b = tmp >> 3;
  const int c = cc * 256 + t;
  const size_t base = (((size_t)b * CHH) * CKW + kw) * CC + c;   // h stride = CKW*CC
  float ar[14], ai[14];
  #pragma unroll
  for (int h = 0; h < 14; h++) {
    ar[h] = Ar[base + (size_t)h * (CKW * CC)];
    ai[h] = Ai[base + (size_t)h * (CKW * CC)];
  }
  float fr[14], fi[14];
  #pragma unroll
  for (int kh = 0; kh < 14; kh++) {
    float yr = 0.f, yi = 0.f;
    #pragma unroll
    for (int h = 0; h < 14; h++) {
      const int m = (h * kh) % 14;
      yr += ar[h] * C14[m] + ai[h] * S14[m];
      yi += ai[h] * C14[m] - ar[h] * S14[m];
    }
    const size_t widx = (((size_t)kh * CKW + kw) * CC + c) * 2;
    const float wr = cw[widx], wi = cw[widx + 1];
    fr[kh] = yr * wr - yi * wi;
    fi[kh] = yr * wi + yi * wr;
  }
  #pragma unroll
  for (int h = 0; h < 14; h++) {
    float sr = 0.f, si = 0.f;
    #pragma unroll
    for (int kh = 0; kh < 14; kh++) {
      const int m = (h * kh) % 14;
      sr += fr[kh] * C14[m] - fi[kh] * S14[m];
      si += fr[kh] * S14[m] + fi[kh] * C14[m];
    }
    Br[base + (size_t)h * (CKW * CC)] = sr;
    Bi[base + (size_t)h * (CKW * CC)] = si;
  }
}

// ---------------- irfft along W (c2r: imag of DC/Nyquist ignored) ----------------
__global__ __launch_bounds__(256)
void fft_w_inv(const float* __restrict__ Br, const float* __restrict__ Bi, float* __restrict__ y2)
{
  const int t = threadIdx.x;
  const int bid = blockIdx.x;
  const int cc = bid & 3;
  const int tmp = bid >> 2;
  const int h = tmp % 14;
  const int b = tmp / 14;
  const int c = cc * 256 + t;
  const size_t ibase = (((size_t)b * CHH + h) * CKW) * CC + c;
  float br[8], bi[8];
  #pragma unroll
  for (int k = 0; k < 8; k++) {
    br[k] = Br[ibase + (size_t)k * CC];
    bi[k] = Bi[ibase + (size_t)k * CC];
  }
  const size_t obase = ((size_t)b * CN + (size_t)h * CWW) * CC + c;
  #pragma unroll
  for (int w = 0; w < 14; w++) {
    float s = br[0] + ((w & 1) ? -br[7] : br[7]);
    #pragma unroll
    for (int k = 1; k < 7; k++) {
      const int m = (w * k) % 14;
      s += 2.0f * (br[k] * C14[m] - bi[k] * S14[m]);
    }
    y2[obase + (size_t)w * CC] = s * (1.0f / 196.0f);   // ortho fwd*inv = 1/196
  }
}

// ---------------- transpose fp32 [R,Cc] -> bf16 [Cc,R] ----------------
__global__ __launch_bounds__(256)
void transpose_f32_bf16(const float* __restrict__ in, unsigned short* __restrict__ out,
                        int R, int Ccols)
{
  __shared__ float tile[32][33];
  const int tx = threadIdx.x & 31;
  const int ty = threadIdx.x >> 5;     // 0..7
  const int cb = blockIdx.x * 32;
  const int rb = blockIdx.y * 32;
  #pragma unroll
  for (int i = 0; i < 32; i += 8)
    tile[ty + i][tx] = in[(size_t)(rb + ty + i) * Ccols + cb + tx];
  __syncthreads();
  #pragma unroll
  for (int i = 0; i < 32; i += 8)
    out[(size_t)(cb + ty + i) * R + rb + tx] = f2bf(tile[tx][ty + i]);
}

// ---------------- 256x256 8-phase bf16 GEMM (T1+T2+T3+T4+T5) ----------------
// C[M,N] = A[M,K] * BT[N,K]^T, +bias, optional exact GELU, bf16 out.
// 512 thr = 8 waves (2M x 4N); BK=64; LDS = 2 bufs x (A 32KB + B 32KB) = 128KB.
// Per K-tile: 4 phases (mh,nh). Phase reads A rows [wm*128+mh*64,+64),
// B rows [wn*64+nh*32,+32). Region death: A-mh0 after ph1, B-nh0 after ph2,
// A-mh1/B-nh1 after ph3. Staging (into the live buffer, dead regions only):
//   ph0: r1=A-mh1(tile T+1) ; ph1: r3=B-nh1(T+1) ; ph2: r0=A-mh0(T+2) ; ph3: r2=B-nh0(T+2)
// One counted vmcnt(4) per K-tile at ph3 (post-stage, pre-barrier) guarantees
// everything staged through ph1(T) landed before any wave reads tile T+1.
// T2 swizzle: read byte ^= (row&7)<<4, realized by inverse-swizzled global
// source col = 8*((u ^ u>>3)&7) with linear global_load_lds dest.
#define STAGE(REG, TILE_, BUF_) do {                                          \
  char* _tb = sm + ((BUF_) << 16) + (((REG) < 2) ? 0 : 32768);                \
  const unsigned short* _g = (((REG) < 2) ? A : BT);                          \
  const int _gb = (((REG) < 2) ? brow : bcol);                                \
  int _r0, _r1;                                                               \
  if ((REG) == 0)      { _r0 = vA;       _r1 = 128 + vA; }                    \
  else if ((REG) == 1) { _r0 = 64 + vA;  _r1 = 192 + vA; }                    \
  else if ((REG) == 2) { _r0 = ((vA>>5)<<6) + (vA&31);      _r1 = _r0 + 128; }\
  else                 { _r0 = ((vA>>5)<<6) + 32 + (vA&31); _r1 = _r0 + 128; }\
  const int _gc = (TILE_) * 64 + cl;                                          \
  gload_lds16(_g + (size_t)(_gb + _r0) * K + _gc, _tb + _r0 * 128 + dcol16);  \
  gload_lds16(_g + (size_t)(_gb + _r1) * K + _gc, _tb + _r1 * 128 + dcol16);  \
} while (0)

template<int DO_GELU>
__global__ __launch_bounds__(512, 2)
void gemm256(const unsigned short* __restrict__ A, const unsigned short* __restrict__ BT,
             const float* __restrict__ bias, unsigned short* __restrict__ C,
             int M, int N, int K)
{
  extern __shared__ __align__(16) char sm[];
  const int t = threadIdx.x;
  const int wid = t >> 6, lane = t & 63;
  const int wm = wid >> 2, wn = wid & 3;
  const int lrow = lane & 15, qk = lane >> 4;
  const int dq = qk << 4;

  // T1: bijective XCD swizzle (m204) + GROUP=4 along N
  const int nbx = N >> 8, nby = M >> 8;
  const int nwg = nbx * nby;
  const int orig = blockIdx.x;
  const int q8 = nwg >> 3, r8 = nwg & 7, xcd = orig & 7, lid = orig >> 3;
  const int wg = (xcd < r8 ? xcd * (q8 + 1) : r8 * (q8 + 1) + (xcd - r8) * q8) + lid;
  const int gw = 4 * nby;
  const int gid = wg / gw, rem = wg % gw;
  const int bx = gid * 4 + (rem & 3);
  const int by = rem >> 2;
  const int brow = by << 8, bcol = bx << 8;
  const int NT = K >> 6;

  // staging per-thread constants
  const int vA = t >> 3;                       // 0..63
  const int cl = ((t ^ (t >> 3)) & 7) << 3;    // inverse-swizzled element col
  const int dcol16 = (t & 7) << 4;             // byte offset within LDS row

  f32x4 acc[8][4] = {};
  bf16x8 af[4][2], bfr[2][2];

  // prologue: stage K-tiles 0 and 1 fully, wait tile 0, publish
  STAGE(0, 0, 0); STAGE(2, 0, 0); STAGE(1, 0, 0); STAGE(3, 0, 0);
  STAGE(0, 1, 1); STAGE(2, 1, 1); STAGE(1, 1, 1); STAGE(3, 1, 1);
  WAITV(8);
  __builtin_amdgcn_s_barrier();

  for (int T = 0; T < NT; ++T) {
    const char* Atile = sm + ((T & 1) << 16);
    const char* Btile = Atile + 32768;
    #pragma unroll
    for (int ph = 0; ph < 4; ++ph) {
      const int mh = ph >> 1, nh = ph & 1;
      // ds-reads for this phase (swizzled)
      if (nh == 0) {
        #pragma unroll
        for (int mf = 0; mf < 4; ++mf) {
          const int row = wm * 128 + mh * 64 + mf * 16 + lrow;
          const int sw = (row & 7) << 4;
          af[mf][0] = *(const bf16x8*)(Atile + row * 128 + ((0  | dq) ^ sw));
          af[mf][1] = *(const bf16x8*)(Atile + row * 128 + ((64 | dq) ^ sw));
        }
      }
      #pragma unroll
      for (int nf = 0; nf < 2; ++nf) {
        const int row = wn * 64 + (nh * 2 + nf) * 16 + lrow;
        const int sw = (row & 7) << 4;
        bfr[nf][0] = *(const bf16x8*)(Btile + row * 128 + ((0  | dq) ^ sw));
        bfr[nf][1] = *(const bf16x8*)(Btile + row * 128 + ((64 | dq) ^ sw));
      }
      // stage one 16KB region into its dead slot
      const int Ts = (ph < 2) ? (T + 1) : (T + 2);
      if (Ts >= 2 && Ts < NT) {
        const int bufb = Ts & 1;
        if (ph == 0)      STAGE(1, Ts, bufb);
        else if (ph == 1) STAGE(3, Ts, bufb);
        else if (ph == 2) STAGE(0, Ts, bufb);
        else              STAGE(2, Ts, bufb);
      }
      // counted vmcnt once per K-tile: publish tile T+1 before its readers
      if (ph == 3 && (T + 1 < NT)) {
        if (T + 2 < NT) { WAITV(4); } else { WAITV(0); }
      }
      __builtin_amdgcn_s_barrier();
      __builtin_amdgcn_s_setprio(1);
      #pragma unroll
      for (int ks = 0; ks < 2; ++ks)
        #pragma unroll
        for (int mf = 0; mf < 4; ++mf)
          #pragma unroll
          for (int nf = 0; nf < 2; ++nf)
            acc[mh * 4 + mf][nh * 2 + nf] = __builtin_amdgcn_mfma_f32_16x16x32_bf16(
                af[mf][ks], bfr[nf][ks], acc[mh * 4 + mf][nh * 2 + nf], 0, 0, 0);
      __builtin_amdgcn_s_setprio(0);
      __builtin_amdgcn_s_barrier();
    }
  }

  // epilogue: bias (+GELU) + bf16 store
  #pragma unroll
  for (int mf = 0; mf < 8; ++mf) {
    #pragma unroll
    for (int nf = 0; nf < 4; ++nf) {
      const int ccol = bcol + wn * 64 + nf * 16 + lrow;
      const float bb = bias[ccol];
      #pragma unroll
      for (int j = 0; j < 4; ++j) {
        const int r = brow + wm * 128 + mf * 16 + qk * 4 + j;
        float v = acc[mf][nf][j] + bb;
        if (DO_GELU) v = 0.5f * v * (1.0f + erff(v * 0.70710678118654752f));
        C[(size_t)r * N + ccol] = f2bf(v);
      }
    }
  }
}

// ---------------- FEM: 3 blockwise instance-norm gates fused + residual ----------------
__device__ __forceinline__ void fem_block(unsigned short* col, int t,
                                          int h0, int nh, int w0, int nw)
{
  float s = 0.f, s2 = 0.f;
  for (int ih = 0; ih < nh; ih++)
    for (int iw = 0; iw < nw; iw++) {
      const float v = bf2f(col[((h0 + ih) * 14 + w0 + iw) * 128 + t]);
      s += v; s2 += v * v;
    }
  const float inv = 1.0f / (float)(nh * nw);
  const float m = s * inv;
  const float var = s2 * inv - m * m;
  const float r = rsqrtf(var + 1e-5f);
  for (int ih = 0; ih < nh; ih++)
    for (int iw = 0; iw < nw; iw++) {
      const int idx = ((h0 + ih) * 14 + w0 + iw) * 128 + t;
      const float v = bf2f(col[idx]);
      const float a = 1.0f / (1.0f + __expf(-(v - m) * r));
      col[idx] = f2bf(0.5f * v * (1.0f + a));
    }
}

__global__ __launch_bounds__(128)
void fem_kernel(const unsigned short* __restrict__ z, const float* __restrict__ x,
                float* __restrict__ out)
{
  __shared__ unsigned short buf[CN * 128];   // 50,176 B; thread-private columns
  const int t = threadIdx.x;
  const int b = blockIdx.x >> 3;
  const int cc = blockIdx.x & 7;
  const int c = cc * 128 + t;
  const size_t base = (size_t)b * CN * CC + c;
  #pragma unroll 4
  for (int n = 0; n < CN; n++) buf[n * 128 + t] = z[base + (size_t)n * CC];
  // s = 3: 5x5 blocks, row/col starts {0,3,6,9,12}, lens {3,3,3,3,2}
  const int st3[5] = {0, 3, 6, 9, 12};
  const int ln3[5] = {3, 3, 3, 3, 2};
  for (int i = 0; i < 5; i++)
    for (int j = 0; j < 5; j++)
      fem_block(buf, t, st3[i], ln3[i], st3[j], ln3[j]);
  // s = 7: 2x2 blocks of 7x7
  for (int i = 0; i < 2; i++)
    for (int j = 0; j < 2; j++)
      fem_block(buf, t, i * 7, 7, j * 7, 7);
  // s = 14: whole field
  fem_block(buf, t, 0, 14, 0, 14);
  #pragma unroll 4
  for (int n = 0; n < CN; n++)
    out[base + (size_t)n * CC] = x[base + (size_t)n * CC] + bf2f(buf[n * 128 + t]);
}

// ---------------- launch ----------------
extern "C" void kernel_launch(void* const* d_in, const int* in_sizes, int n_in,
                              void* d_out, int out_size, void* d_ws, size_t ws_size,
                              hipStream_t stream) {
  const float* x     = (const float*)d_in[0];
  const float* ln1_g = (const float*)d_in[1];
  const float* ln1_b = (const float*)d_in[2];
  const float* cw    = (const float*)d_in[3];
  const float* ln2_g = (const float*)d_in[4];
  const float* ln2_b = (const float*)d_in[5];
  const float* fc1_w = (const float*)d_in[6];
  const float* fc1_b = (const float*)d_in[7];
  const float* fc2_w = (const float*)d_in[8];
  const float* fc2_b = (const float*)d_in[9];
  float* out = (float*)d_out;
  char* ws = (char*)d_ws;

  // arena (total 161.5 MB); d_out doubles as fp32 scratch for y1/y2
  const size_t SZ_A = (size_t)CB * CHH * CKW * CC * 4;       // 29,360,128 B
  float* Ar = (float*)(ws);
  float* Ai = (float*)(ws + SZ_A);
  float* Br = (float*)(ws + 2 * SZ_A);
  float* Bi = (float*)(ws + 3 * SZ_A);
  unsigned short* A1   = (unsigned short*)(ws);                        // after FFT done
  unsigned short* W1T  = (unsigned short*)(ws + SZ_A);                 // [4096,1024] bf16
  unsigned short* W2T  = (unsigned short*)(ws + SZ_A + (size_t)4096 * 1024 * 2); // [1024,4096]
  unsigned short* Hmid = (unsigned short*)(ws + 2 * SZ_A);             // [12544,4096] bf16
  unsigned short* Z    = (unsigned short*)(ws);                        // [12544,1024] bf16

  // allow 128KB dynamic LDS for the GEMMs (no-op if unnecessary)
  static bool attr_done = false;
  if (!attr_done) {
    hipFuncSetAttribute((const void*)gemm256<1>,
                        hipFuncAttributeMaxDynamicSharedMemorySize, 131072);
    hipFuncSetAttribute((const void*)gemm256<0>,
                        hipFuncAttributeMaxDynamicSharedMemorySize, 131072);
    attr_done = true;
  }

  // 1. LN1: x -> y1 (in d_out)
  ln_kernel<0><<<CROWS, 256, 0, stream>>>(x, ln1_g, ln1_b, out, nullptr);
  // 2. rfft along W
  fft_w_fwd<<<CB * CHH * 4, 256, 0, stream>>>(out, Ar, Ai);
  // 3. fft along H + filter + ifft along H
  fft_h_filt<<<CB * CKW * 4, 256, 0, stream>>>(Ar, Ai, cw, Br, Bi);
  // 4. irfft along W -> y2 (in d_out)
  fft_w_inv<<<CB * CHH * 4, 256, 0, stream>>>(Br, Bi, out);
  // 5. LN2 -> bf16 A1
  ln_kernel<1><<<CROWS, 256, 0, stream>>>(out, ln2_g, ln2_b, nullptr, A1);
  // 6. weight prep (FFT intermediates dead)
  transpose_f32_bf16<<<dim3(4096 / 32, 1024 / 32), 256, 0, stream>>>(fc1_w, W1T, 1024, 4096);
  transpose_f32_bf16<<<dim3(1024 / 32, 4096 / 32), 256, 0, stream>>>(fc2_w, W2T, 4096, 1024);
  // 7. GEMM1 + bias + exact GELU -> Hmid bf16 (grid 16x49=784)
  gemm256<1><<<dim3(784), 512, 131072, stream>>>(A1, W1T, fc1_b, Hmid, CROWS, 4096, 1024);
  // 8. GEMM2 + bias -> Z bf16 (grid 4x49=196)
  gemm256<0><<<dim3(196), 512, 131072, stream>>>(Hmid, W2T, fc2_b, Z, CROWS, 1024, 4096);
  // 9. FEM x3 fused + residual -> out
  fem_kernel<<<CB * 8, 128, 0, stream>>>(Z, x, out);
}

// Round 3
// 516.244 us; speedup vs baseline: 1.1825x; 1.0038x over previous
//
#include <hip/hip_runtime.h>

// ---------------- problem constants ----------------
constexpr int CB = 64;          // batch
constexpr int CHH = 14, CWW = 14;
constexpr int CN = 196;         // CHH*CWW
constexpr int CC = 1024;        // channels
constexpr int CROWS = CB * CN;  // 12544
constexpr int CKW = 8;          // rfft bins along W

// twiddles: cos/sin(2*pi*m/14), m=0..13
constexpr float C14[14] = {
  1.0f, 0.9009688679024191f, 0.6234898018587336f, 0.2225209339563144f,
  -0.2225209339563144f, -0.6234898018587336f, -0.9009688679024191f, -1.0f,
  -0.9009688679024191f, -0.6234898018587336f, -0.2225209339563144f,
  0.2225209339563144f, 0.6234898018587336f, 0.9009688679024191f };
constexpr float S14[14] = {
  0.0f, 0.4338837391175581f, 0.7818314824680298f, 0.9749279121818236f,
  0.9749279121818236f, 0.7818314824680298f, 0.4338837391175581f, 0.0f,
  -0.4338837391175581f, -0.7818314824680298f, -0.9749279121818236f,
  -0.9749279121818236f, -0.7818314824680298f, -0.4338837391175581f };

typedef __attribute__((ext_vector_type(8))) short bf16x8;
typedef __attribute__((ext_vector_type(4))) float f32x4;

__device__ __forceinline__ unsigned short f2bf(float f) {
  unsigned u = __builtin_bit_cast(unsigned, f);
  u += 0x7FFFu + ((u >> 16) & 1u);   // RNE
  return (unsigned short)(u >> 16);
}
__device__ __forceinline__ float bf2f(unsigned short h) {
  return __builtin_bit_cast(float, (unsigned)h << 16);
}

__device__ __forceinline__ void gload_lds16(const void* g, void* l) {
  __builtin_amdgcn_global_load_lds(
      (const __attribute__((address_space(1))) void*)g,
      (__attribute__((address_space(3))) void*)l, 16, 0, 0);
}

#define WAITV(N)  asm volatile("s_waitcnt vmcnt(" #N ")" ::: "memory")
#define SBAR()    asm volatile("s_barrier" ::: "memory")
#define WAITLGKM0() asm volatile("s_waitcnt lgkmcnt(0)" ::: "memory")

// ---------------- LayerNorm over C=1024 (one block per row) ----------------
template<int OUTBF>
__global__ __launch_bounds__(256)
void ln_kernel(const float* __restrict__ in, const float* __restrict__ gam,
               const float* __restrict__ bet, float* __restrict__ outf,
               unsigned short* __restrict__ outb)
{
  const int row = blockIdx.x;
  const int t = threadIdx.x;
  const float4 v = *(const float4*)(in + (size_t)row * CC + t * 4);
  float s  = v.x + v.y + v.z + v.w;
  float s2 = v.x*v.x + v.y*v.y + v.z*v.z + v.w*v.w;
  #pragma unroll
  for (int o = 32; o > 0; o >>= 1) { s += __shfl_down(s, o); s2 += __shfl_down(s2, o); }
  __shared__ float red[8];
  const int wid = t >> 6, lane = t & 63;
  if (lane == 0) { red[wid] = s; red[4 + wid] = s2; }
  __syncthreads();
  s  = red[0] + red[1] + red[2] + red[3];
  s2 = red[4] + red[5] + red[6] + red[7];
  const float mean = s * (1.0f / CC);
  const float var  = s2 * (1.0f / CC) - mean * mean;
  const float r = rsqrtf(var + 1e-5f);
  const float4 g4 = *(const float4*)(gam + t * 4);
  const float4 b4 = *(const float4*)(bet + t * 4);
  const float o0 = (v.x - mean) * r * g4.x + b4.x;
  const float o1 = (v.y - mean) * r * g4.y + b4.y;
  const float o2 = (v.z - mean) * r * g4.z + b4.z;
  const float o3 = (v.w - mean) * r * g4.w + b4.w;
  if (OUTBF) {
    ushort4 p; p.x = f2bf(o0); p.y = f2bf(o1); p.z = f2bf(o2); p.w = f2bf(o3);
    *(ushort4*)(outb + (size_t)row * CC + t * 4) = p;
  } else {
    *(float4*)(outf + (size_t)row * CC + t * 4) = make_float4(o0, o1, o2, o3);
  }
}

// ---------------- rfft along W: [B,H,W,C] real -> [B,H,8,C] complex ----------------
__global__ __launch_bounds__(256)
void fft_w_fwd(const float* __restrict__ y, float* __restrict__ Ar, float* __restrict__ Ai)
{
  const int t = threadIdx.x;
  const int bid = blockIdx.x;      // ((b*14)+h)*4 + cc
  const int cc = bid & 3;
  const int tmp = bid >> 2;
  const int h = tmp % 14;
  const int b = tmp / 14;
  const int c = cc * 256 + t;
  const size_t base = ((size_t)b * CN + (size_t)h * CWW) * CC + c;
  float v[14];
  #pragma unroll
  for (int w = 0; w < 14; w++) v[w] = y[base + (size_t)w * CC];
  const size_t obase = (((size_t)b * CHH + h) * CKW) * CC + c;
  #pragma unroll
  for (int kw = 0; kw < 8; kw++) {
    float sr = 0.f, si = 0.f;
    #pragma unroll
    for (int w = 0; w < 14; w++) {
      const int m = (w * kw) % 14;
      sr += v[w] * C14[m];
      si -= v[w] * S14[m];
    }
    Ar[obase + (size_t)kw * CC] = sr;
    Ai[obase + (size_t)kw * CC] = si;
  }
}

// ---------------- fft along H + complex filter + ifft along H ----------------
__global__ __launch_bounds__(256)
void fft_h_filt(const float* __restrict__ Ar, const float* __restrict__ Ai,
                const float* __restrict__ cw, float* __restrict__ Br, float* __restrict__ Bi)
{
  const int t = threadIdx.x;
  const int bid = blockIdx.x;      // ((b*8)+kw)*4 + cc
  const int cc = bid & 3;
  const int tmp = bid >> 2;
  const int kw = tmp & 7;
  const int b = tmp >> 3;
  const int c = cc * 256 + t;
  const size_t base = (((size_t)b * CHH) * CKW + kw) * CC + c;   // h stride = CKW*CC
  float ar[14], ai[14];
  #pragma unroll
  for (int h = 0; h < 14; h++) {
    ar[h] = Ar[base + (size_t)h * (CKW * CC)];
    ai[h] = Ai[base + (size_t)h * (CKW * CC)];
  }
  float fr[14], fi[14];
  #pragma unroll
  for (int kh = 0; kh < 14; kh++) {
    float yr = 0.f, yi = 0.f;
    #pragma unroll
    for (int h = 0; h < 14; h++) {
      const int m = (h * kh) % 14;
      yr += ar[h] * C14[m] + ai[h] * S14[m];
      yi += ai[h] * C14[m] - ar[h] * S14[m];
    }
    const size_t widx = (((size_t)kh * CKW + kw) * CC + c) * 2;
    const float wr = cw[widx], wi = cw[widx + 1];
    fr[kh] = yr * wr - yi * wi;
    fi[kh] = yr * wi + yi * wr;
  }
  #pragma unroll
  for (int h = 0; h < 14; h++) {
    float sr = 0.f, si = 0.f;
    #pragma unroll
    for (int kh = 0; kh < 14; kh++) {
      const int m = (h * kh) % 14;
      sr += fr[kh] * C14[m] - fi[kh] * S14[m];
      si += fr[kh] * S14[m] + fi[kh] * C14[m];
    }
    Br[base + (size_t)h * (CKW * CC)] = sr;
    Bi[base + (size_t)h * (CKW * CC)] = si;
  }
}

// ---------------- irfft along W (c2r: imag of DC/Nyquist ignored) ----------------
__global__ __launch_bounds__(256)
void fft_w_inv(const float* __restrict__ Br, const float* __restrict__ Bi, float* __restrict__ y2)
{
  const int t = threadIdx.x;
  const int bid = blockIdx.x;
  const int cc = bid & 3;
  const int tmp = bid >> 2;
  const int h = tmp % 14;
  const int b = tmp / 14;
  const int c = cc * 256 + t;
  const size_t ibase = (((size_t)b * CHH + h) * CKW) * CC + c;
  float br[8], bi[8];
  #pragma unroll
  for (int k = 0; k < 8; k++) {
    br[k] = Br[ibase + (size_t)k * CC];
    bi[k] = Bi[ibase + (size_t)k * CC];
  }
  const size_t obase = ((size_t)b * CN + (size_t)h * CWW) * CC + c;
  #pragma unroll
  for (int w = 0; w < 14; w++) {
    float s = br[0] + ((w & 1) ? -br[7] : br[7]);
    #pragma unroll
    for (int k = 1; k < 7; k++) {
      const int m = (w * k) % 14;
      s += 2.0f * (br[k] * C14[m] - bi[k] * S14[m]);
    }
    y2[obase + (size_t)w * CC] = s * (1.0f / 196.0f);   // ortho fwd*inv = 1/196
  }
}

// ---------------- transpose fp32 [R,Cc] -> bf16 [Cc,R] ----------------
__global__ __launch_bounds__(256)
void transpose_f32_bf16(const float* __restrict__ in, unsigned short* __restrict__ out,
                        int R, int Ccols)
{
  __shared__ float tile[32][33];
  const int tx = threadIdx.x & 31;
  const int ty = threadIdx.x >> 5;     // 0..7
  const int cb = blockIdx.x * 32;
  const int rb = blockIdx.y * 32;
  #pragma unroll
  for (int i = 0; i < 32; i += 8)
    tile[ty + i][tx] = in[(size_t)(rb + ty + i) * Ccols + cb + tx];
  __syncthreads();
  #pragma unroll
  for (int i = 0; i < 32; i += 8)
    out[(size_t)(cb + ty + i) * R + rb + tx] = f2bf(tile[tx][ty + i]);
}

// ---------------- 256x256 8-phase bf16 GEMM (T1..T5, JIT-counted vmcnt) ----------------
// C[M,N] = A[M,K] * BT[N,K]^T, +bias, optional exact GELU, bf16 out.
// 512 thr = 8 waves (2M x 4N); BK=64; LDS = 2 bufs x (A 32KB + B 32KB) = 128KB.
// Phases per K-tile (mh,nh): ph0=(0,0) ph1=(0,1) ph2=(1,0) ph3=(1,1).
// Region reads: A-mh0 @ph0,ph1; A-mh1 @ph2,ph3; B-nh0 @ph0,ph2; B-nh1 @ph1,ph3.
// Staging during tile T: ph0->A-mh1(T+1), ph1->B-nh1(T+1) (other buffer, dead since
// tile T-1); ph2->A-mh0(T+2), ph3->B-nh0(T+2) (this buffer, just died).
// Issue ledger (2 loads/stage, 8/tile steady): region of tile T staged at
//   A-mh0: ph2(T-2)  B-nh0: ph3(T-2)  A-mh1: ph0(T-1)  B-nh1: ph1(T-1)
// Just-in-time counted waits before the entry barrier of each phase of tile T:
//   ph0: vmcnt(10)  [newest 10 = ph0(T)+tile(T-1)'s 8 -> A-mh0,B-nh0 landed]
//   ph1: vmcnt(8)   [newest 8 = ph1,ph0(T)+ph3,ph2(T-1) -> B-nh1 landed]
//   ph2: vmcnt(12)  [newest 12 = ph2..0(T)+tile(T-1)+... -> A-mh1 landed]
//   ph3: none
// Tail (T >= NT-2): skipped stages break the constants -> full drain at ph0.
#define STAGE(REG, TILE_, BUF_) do {                                          \
  char* _tb = sm + ((BUF_) << 16) + (((REG) < 2) ? 0 : 32768);                \
  const unsigned short* _g = (((REG) < 2) ? A : BT);                          \
  const int _gb = (((REG) < 2) ? brow : bcol);                                \
  int _r0, _r1;                                                               \
  if ((REG) == 0)      { _r0 = vA;       _r1 = 128 + vA; }                    \
  else if ((REG) == 1) { _r0 = 64 + vA;  _r1 = 192 + vA; }                    \
  else if ((REG) == 2) { _r0 = ((vA>>5)<<6) + (vA&31);      _r1 = _r0 + 128; }\
  else                 { _r0 = ((vA>>5)<<6) + 32 + (vA&31); _r1 = _r0 + 128; }\
  const int _gc = (TILE_) * 64 + cl;                                          \
  gload_lds16(_g + (size_t)(_gb + _r0) * K + _gc, _tb + _r0 * 128 + dcol16);  \
  gload_lds16(_g + (size_t)(_gb + _r1) * K + _gc, _tb + _r1 * 128 + dcol16);  \
} while (0)

// One phase of one K-tile. BUF is a compile-time 0/1 (loop unrolled x2).
#define PHASE(TT, BUF, PH) do {                                               \
  const char* At_ = sm + ((BUF) << 16);                                       \
  const char* Bt_ = At_ + 32768;                                              \
  if (((PH) & 1) == 0) {                                                      \
    const int mh_ = (PH) >> 1;                                                \
    _Pragma("unroll")                                                         \
    for (int mf = 0; mf < 4; ++mf) {                                          \
      const int row = wm * 128 + mh_ * 64 + mf * 16 + lrow;                   \
      const int sw = (row & 7) << 4;                                          \
      af[mf][0] = *(const bf16x8*)(At_ + row * 128 + ((0  | dq) ^ sw));       \
      af[mf][1] = *(const bf16x8*)(At_ + row * 128 + ((64 | dq) ^ sw));       \
    }                                                                         \
  }                                                                           \
  {                                                                           \
    const int nh_ = (PH) & 1;                                                 \
    _Pragma("unroll")                                                         \
    for (int nf = 0; nf < 2; ++nf) {                                          \
      const int row = wn * 64 + (nh_ * 2 + nf) * 16 + lrow;                   \
      const int sw = (row & 7) << 4;                                          \
      bfr[nf][0] = *(const bf16x8*)(Bt_ + row * 128 + ((0  | dq) ^ sw));      \
      bfr[nf][1] = *(const bf16x8*)(Bt_ + row * 128 + ((64 | dq) ^ sw));      \
    }                                                                         \
  }                                                                           \
  if ((PH) == 0)      { if ((TT) + 1 >= 2 && (TT) + 1 < NT) STAGE(1, (TT)+1, (BUF)^1); } \
  else if ((PH) == 1) { if ((TT) + 1 >= 2 && (TT) + 1 < NT) STAGE(3, (TT)+1, (BUF)^1); } \
  else if ((PH) == 2) { if ((TT) + 2 < NT) STAGE(0, (TT)+2, (BUF)); }         \
  else                { if ((TT) + 2 < NT) STAGE(2, (TT)+2, (BUF)); }         \
  if ((PH) == 0)      { if ((TT) >= NT - 2) { WAITV(0); } else { WAITV(10); } } \
  else if ((PH) == 1) { if ((TT) < NT - 2) { WAITV(8); } }                    \
  else if ((PH) == 2) { if ((TT) < NT - 2) { WAITV(12); } }                   \
  SBAR();                                                                     \
  WAITLGKM0();                                                                \
  __builtin_amdgcn_s_setprio(1);                                              \
  {                                                                           \
    const int mh_ = (PH) >> 1, nh_ = (PH) & 1;                                \
    _Pragma("unroll")                                                         \
    for (int ks = 0; ks < 2; ++ks)                                            \
      _Pragma("unroll")                                                       \
      for (int mf = 0; mf < 4; ++mf)                                          \
        _Pragma("unroll")                                                     \
        for (int nf = 0; nf < 2; ++nf)                                        \
          acc[mh_ * 4 + mf][nh_ * 2 + nf] = __builtin_amdgcn_mfma_f32_16x16x32_bf16( \
              af[mf][ks], bfr[nf][ks], acc[mh_ * 4 + mf][nh_ * 2 + nf], 0, 0, 0); \
  }                                                                           \
  __builtin_amdgcn_s_setprio(0);                                              \
  SBAR();                                                                     \
} while (0)

#define KTILE(TT, BUF) do {                                                   \
  PHASE(TT, BUF, 0); PHASE(TT, BUF, 1); PHASE(TT, BUF, 2); PHASE(TT, BUF, 3); \
} while (0)

template<int DO_GELU>
__global__ __launch_bounds__(512, 2)
void gemm256(const unsigned short* __restrict__ A, const unsigned short* __restrict__ BT,
             const float* __restrict__ bias, unsigned short* __restrict__ C,
             int M, int N, int K)
{
  extern __shared__ __align__(16) char sm[];
  const int t = threadIdx.x;
  const int wid = t >> 6, lane = t & 63;
  const int wm = wid >> 2, wn = wid & 3;
  const int lrow = lane & 15, qk = lane >> 4;
  const int dq = qk << 4;

  // T1: bijective XCD swizzle (m204) + GROUP=4 along N
  const int nbx = N >> 8, nby = M >> 8;
  const int nwg = nbx * nby;
  const int orig = blockIdx.x;
  const int q8 = nwg >> 3, r8 = nwg & 7, xcd = orig & 7, lid = orig >> 3;
  const int wg = (xcd < r8 ? xcd * (q8 + 1) : r8 * (q8 + 1) + (xcd - r8) * q8) + lid;
  const int gw = 4 * nby;
  const int gid = wg / gw, rem = wg % gw;
  const int bx = gid * 4 + (rem & 3);
  const int by = rem >> 2;
  const int brow = by << 8, bcol = bx << 8;
  const int NT = K >> 6;

  // staging per-thread constants
  const int vA = t >> 3;                       // 0..63
  const int cl = ((t ^ (t >> 3)) & 7) << 3;    // inverse-swizzled element col
  const int dcol16 = (t & 7) << 4;             // byte offset within LDS row

  f32x4 acc[8][4] = {};
  bf16x8 af[4][2], bfr[2][2];

  // prologue: stage K-tiles 0 and 1 fully, wait tile 0, publish
  STAGE(0, 0, 0); STAGE(2, 0, 0); STAGE(1, 0, 0); STAGE(3, 0, 0);
  STAGE(0, 1, 1); STAGE(2, 1, 1); STAGE(1, 1, 1); STAGE(3, 1, 1);
  WAITV(8);
  SBAR();

  for (int T = 0; T < NT; T += 2) {
    KTILE(T, 0);
    KTILE(T + 1, 1);
  }

  // epilogue: bias (+GELU) + bf16 store
  #pragma unroll
  for (int mf = 0; mf < 8; ++mf) {
    #pragma unroll
    for (int nf = 0; nf < 4; ++nf) {
      const int ccol = bcol + wn * 64 + nf * 16 + lrow;
      const float bb = bias[ccol];
      #pragma unroll
      for (int j = 0; j < 4; ++j) {
        const int r = brow + wm * 128 + mf * 16 + qk * 4 + j;
        float v = acc[mf][nf][j] + bb;
        if (DO_GELU) v = 0.5f * v * (1.0f + erff(v * 0.70710678118654752f));
        C[(size_t)r * N + ccol] = f2bf(v);
      }
    }
  }
}

// ---------------- FEM: 3 blockwise instance-norm gates fused + residual ----------------
__device__ __forceinline__ void fem_block(unsigned short* col, int t,
                                          int h0, int nh, int w0, int nw)
{
  float s = 0.f, s2 = 0.f;
  for (int ih = 0; ih < nh; ih++)
    for (int iw = 0; iw < nw; iw++) {
      const float v = bf2f(col[((h0 + ih) * 14 + w0 + iw) * 128 + t]);
      s += v; s2 += v * v;
    }
  const float inv = 1.0f / (float)(nh * nw);
  const float m = s * inv;
  const float var = s2 * inv - m * m;
  const float r = rsqrtf(var + 1e-5f);
  for (int ih = 0; ih < nh; ih++)
    for (int iw = 0; iw < nw; iw++) {
      const int idx = ((h0 + ih) * 14 + w0 + iw) * 128 + t;
      const float v = bf2f(col[idx]);
      const float a = 1.0f / (1.0f + __expf(-(v - m) * r));
      col[idx] = f2bf(0.5f * v * (1.0f + a));
    }
}

__global__ __launch_bounds__(128)
void fem_kernel(const unsigned short* __restrict__ z, const float* __restrict__ x,
                float* __restrict__ out)
{
  __shared__ unsigned short buf[CN * 128];   // 50,176 B; thread-private columns
  const int t = threadIdx.x;
  const int b = blockIdx.x >> 3;
  const int cc = blockIdx.x & 7;
  const int c = cc * 128 + t;
  const size_t base = (size_t)b * CN * CC + c;
  #pragma unroll 4
  for (int n = 0; n < CN; n++) buf[n * 128 + t] = z[base + (size_t)n * CC];
  // s = 3: 5x5 blocks, row/col starts {0,3,6,9,12}, lens {3,3,3,3,2}
  const int st3[5] = {0, 3, 6, 9, 12};
  const int ln3[5] = {3, 3, 3, 3, 2};
  for (int i = 0; i < 5; i++)
    for (int j = 0; j < 5; j++)
      fem_block(buf, t, st3[i], ln3[i], st3[j], ln3[j]);
  // s = 7: 2x2 blocks of 7x7
  for (int i = 0; i < 2; i++)
    for (int j = 0; j < 2; j++)
      fem_block(buf, t, i * 7, 7, j * 7, 7);
  // s = 14: whole field
  fem_block(buf, t, 0, 14, 0, 14);
  #pragma unroll 4
  for (int n = 0; n < CN; n++)
    out[base + (size_t)n * CC] = x[base + (size_t)n * CC] + bf2f(buf[n * 128 + t]);
}

// ---------------- launch ----------------
extern "C" void kernel_launch(void* const* d_in, const int* in_sizes, int n_in,
                              void* d_out, int out_size, void* d_ws, size_t ws_size,
                              hipStream_t stream) {
  const float* x     = (const float*)d_in[0];
  const float* ln1_g = (const float*)d_in[1];
  const float* ln1_b = (const float*)d_in[2];
  const float* cw    = (const float*)d_in[3];
  const float* ln2_g = (const float*)d_in[4];
  const float* ln2_b = (const float*)d_in[5];
  const float* fc1_w = (const float*)d_in[6];
  const float* fc1_b = (const float*)d_in[7];
  const float* fc2_w = (const float*)d_in[8];
  const float* fc2_b = (const float*)d_in[9];
  float* out = (float*)d_out;
  char* ws = (char*)d_ws;

  // arena (total 161.5 MB); d_out doubles as fp32 scratch for y1/y2
  const size_t SZ_A = (size_t)CB * CHH * CKW * CC * 4;       // 29,360,128 B
  float* Ar = (float*)(ws);
  float* Ai = (float*)(ws + SZ_A);
  float* Br = (float*)(ws + 2 * SZ_A);
  float* Bi = (float*)(ws + 3 * SZ_A);
  unsigned short* A1   = (unsigned short*)(ws);                        // after FFT done
  unsigned short* W1T  = (unsigned short*)(ws + SZ_A);                 // [4096,1024] bf16
  unsigned short* W2T  = (unsigned short*)(ws + SZ_A + (size_t)4096 * 1024 * 2); // [1024,4096]
  unsigned short* Hmid = (unsigned short*)(ws + 2 * SZ_A);             // [12544,4096] bf16
  unsigned short* Z    = (unsigned short*)(ws);                        // [12544,1024] bf16

  // allow 128KB dynamic LDS for the GEMMs
  static bool attr_done = false;
  if (!attr_done) {
    hipFuncSetAttribute((const void*)gemm256<1>,
                        hipFuncAttributeMaxDynamicSharedMemorySize, 131072);
    hipFuncSetAttribute((const void*)gemm256<0>,
                        hipFuncAttributeMaxDynamicSharedMemorySize, 131072);
    attr_done = true;
  }

  // 1. LN1: x -> y1 (in d_out)
  ln_kernel<0><<<CROWS, 256, 0, stream>>>(x, ln1_g, ln1_b, out, nullptr);
  // 2. rfft along W
  fft_w_fwd<<<CB * CHH * 4, 256, 0, stream>>>(out, Ar, Ai);
  // 3. fft along H + filter + ifft along H
  fft_h_filt<<<CB * CKW * 4, 256, 0, stream>>>(Ar, Ai, cw, Br, Bi);
  // 4. irfft along W -> y2 (in d_out)
  fft_w_inv<<<CB * CHH * 4, 256, 0, stream>>>(Br, Bi, out);
  // 5. LN2 -> bf16 A1
  ln_kernel<1><<<CROWS, 256, 0, stream>>>(out, ln2_g, ln2_b, nullptr, A1);
  // 6. weight prep (FFT intermediates dead)
  transpose_f32_bf16<<<dim3(4096 / 32, 1024 / 32), 256, 0, stream>>>(fc1_w, W1T, 1024, 4096);
  transpose_f32_bf16<<<dim3(1024 / 32, 4096 / 32), 256, 0, stream>>>(fc2_w, W2T, 4096, 1024);
  // 7. GEMM1 + bias + exact GELU -> Hmid bf16 (grid 16x49=784)
  gemm256<1><<<dim3(784), 512, 131072, stream>>>(A1, W1T, fc1_b, Hmid, CROWS, 4096, 1024);
  // 8. GEMM2 + bias -> Z bf16 (grid 4x49=196)
  gemm256<0><<<dim3(196), 512, 131072, stream>>>(Hmid, W2T, fc2_b, Z, CROWS, 1024, 4096);
  // 9. FEM x3 fused + residual -> out
  fem_kernel<<<CB * 8, 128, 0, stream>>>(Z, x, out);
}

// Round 4
// 493.376 us; speedup vs baseline: 1.2373x; 1.0464x over previous
//
#include <hip/hip_runtime.h>

// ---------------- problem constants ----------------
constexpr int CB = 64;          // batch
constexpr int CHH = 14, CWW = 14;
constexpr int CN = 196;         // CHH*CWW
constexpr int CC = 1024;        // channels
constexpr int CROWS = CB * CN;  // 12544
constexpr int CKW = 8;          // rfft bins along W

// twiddles: cos/sin(2*pi*m/14), m=0..13
constexpr float C14[14] = {
  1.0f, 0.9009688679024191f, 0.6234898018587336f, 0.2225209339563144f,
  -0.2225209339563144f, -0.6234898018587336f, -0.9009688679024191f, -1.0f,
  -0.9009688679024191f, -0.6234898018587336f, -0.2225209339563144f,
  0.2225209339563144f, 0.6234898018587336f, 0.9009688679024191f };
constexpr float S14[14] = {
  0.0f, 0.4338837391175581f, 0.7818314824680298f, 0.9749279121818236f,
  0.9749279121818236f, 0.7818314824680298f, 0.4338837391175581f, 0.0f,
  -0.4338837391175581f, -0.7818314824680298f, -0.9749279121818236f,
  -0.9749279121818236f, -0.7818314824680298f, -0.4338837391175581f };

typedef __attribute__((ext_vector_type(8))) short bf16x8;
typedef __attribute__((ext_vector_type(4))) float f32x4;

__device__ __forceinline__ unsigned short f2bf(float f) {
  unsigned u = __builtin_bit_cast(unsigned, f);
  u += 0x7FFFu + ((u >> 16) & 1u);   // RNE
  return (unsigned short)(u >> 16);
}
__device__ __forceinline__ float bf2f(unsigned short h) {
  return __builtin_bit_cast(float, (unsigned)h << 16);
}

__device__ __forceinline__ void gload_lds16(const void* g, void* l) {
  __builtin_amdgcn_global_load_lds(
      (const __attribute__((address_space(1))) void*)g,
      (__attribute__((address_space(3))) void*)l, 16, 0, 0);
}

#define WAITV(N)  asm volatile("s_waitcnt vmcnt(" #N ")" ::: "memory")
#define SBAR()    asm volatile("s_barrier" ::: "memory")
#define WAITLGKM0() asm volatile("s_waitcnt lgkmcnt(0)" ::: "memory")

// ---------------- LayerNorm over C=1024 (one block per row) ----------------
template<int OUTBF>
__global__ __launch_bounds__(256)
void ln_kernel(const float* __restrict__ in, const float* __restrict__ gam,
               const float* __restrict__ bet, float* __restrict__ outf,
               unsigned short* __restrict__ outb)
{
  const int row = blockIdx.x;
  const int t = threadIdx.x;
  const float4 v = *(const float4*)(in + (size_t)row * CC + t * 4);
  float s  = v.x + v.y + v.z + v.w;
  float s2 = v.x*v.x + v.y*v.y + v.z*v.z + v.w*v.w;
  #pragma unroll
  for (int o = 32; o > 0; o >>= 1) { s += __shfl_down(s, o); s2 += __shfl_down(s2, o); }
  __shared__ float red[8];
  const int wid = t >> 6, lane = t & 63;
  if (lane == 0) { red[wid] = s; red[4 + wid] = s2; }
  __syncthreads();
  s  = red[0] + red[1] + red[2] + red[3];
  s2 = red[4] + red[5] + red[6] + red[7];
  const float mean = s * (1.0f / CC);
  const float var  = s2 * (1.0f / CC) - mean * mean;
  const float r = rsqrtf(var + 1e-5f);
  const float4 g4 = *(const float4*)(gam + t * 4);
  const float4 b4 = *(const float4*)(bet + t * 4);
  const float o0 = (v.x - mean) * r * g4.x + b4.x;
  const float o1 = (v.y - mean) * r * g4.y + b4.y;
  const float o2 = (v.z - mean) * r * g4.z + b4.z;
  const float o3 = (v.w - mean) * r * g4.w + b4.w;
  if (OUTBF) {
    ushort4 p; p.x = f2bf(o0); p.y = f2bf(o1); p.z = f2bf(o2); p.w = f2bf(o3);
    *(ushort4*)(outb + (size_t)row * CC + t * 4) = p;
  } else {
    *(float4*)(outf + (size_t)row * CC + t * 4) = make_float4(o0, o1, o2, o3);
  }
}

// ---------------- rfft along W: [B,H,W,C] real -> [B,H,8,C] complex ----------------
__global__ __launch_bounds__(256)
void fft_w_fwd(const float* __restrict__ y, float* __restrict__ Ar, float* __restrict__ Ai)
{
  const int t = threadIdx.x;
  const int bid = blockIdx.x;      // ((b*14)+h)*4 + cc
  const int cc = bid & 3;
  const int tmp = bid >> 2;
  const int h = tmp % 14;
  const int b = tmp / 14;
  const int c = cc * 256 + t;
  const size_t base = ((size_t)b * CN + (size_t)h * CWW) * CC + c;
  float v[14];
  #pragma unroll
  for (int w = 0; w < 14; w++) v[w] = y[base + (size_t)w * CC];
  const size_t obase = (((size_t)b * CHH + h) * CKW) * CC + c;
  #pragma unroll
  for (int kw = 0; kw < 8; kw++) {
    float sr = 0.f, si = 0.f;
    #pragma unroll
    for (int w = 0; w < 14; w++) {
      const int m = (w * kw) % 14;
      sr += v[w] * C14[m];
      si -= v[w] * S14[m];
    }
    Ar[obase + (size_t)kw * CC] = sr;
    Ai[obase + (size_t)kw * CC] = si;
  }
}

// ---------------- fft along H + complex filter + ifft along H ----------------
__global__ __launch_bounds__(256)
void fft_h_filt(const float* __restrict__ Ar, const float* __restrict__ Ai,
                const float* __restrict__ cw, float* __restrict__ Br, float* __restrict__ Bi)
{
  const int t = threadIdx.x;
  const int bid = blockIdx.x;      // ((b*8)+kw)*4 + cc
  const int cc = bid & 3;
  const int tmp = bid >> 2;
  const int kw = tmp & 7;
  const int b = tmp >> 3;
  const int c = cc * 256 + t;
  const size_t base = (((size_t)b * CHH) * CKW + kw) * CC + c;   // h stride = CKW*CC
  float ar[14], ai[14];
  #pragma unroll
  for (int h = 0; h < 14; h++) {
    ar[h] = Ar[base + (size_t)h * (CKW * CC)];
    ai[h] = Ai[base + (size_t)h * (CKW * CC)];
  }
  float fr[14], fi[14];
  #pragma unroll
  for (int kh = 0; kh < 14; kh++) {
    float yr = 0.f, yi = 0.f;
    #pragma unroll
    for (int h = 0; h < 14; h++) {
      const int m = (h * kh) % 14;
      yr += ar[h] * C14[m] + ai[h] * S14[m];
      yi += ai[h] * C14[m] - ar[h] * S14[m];
    }
    const size_t widx = (((size_t)kh * CKW + kw) * CC + c) * 2;
    const float wr = cw[widx], wi = cw[widx + 1];
    fr[kh] = yr * wr - yi * wi;
    fi[kh] = yr * wi + yi * wr;
  }
  #pragma unroll
  for (int h = 0; h < 14; h++) {
    float sr = 0.f, si = 0.f;
    #pragma unroll
    for (int kh = 0; kh < 14; kh++) {
      const int m = (h * kh) % 14;
      sr += fr[kh] * C14[m] - fi[kh] * S14[m];
      si += fr[kh] * S14[m] + fi[kh] * C14[m];
    }
    Br[base + (size_t)h * (CKW * CC)] = sr;
    Bi[base + (size_t)h * (CKW * CC)] = si;
  }
}

// ---------------- irfft along W (c2r: imag of DC/Nyquist ignored) ----------------
__global__ __launch_bounds__(256)
void fft_w_inv(const float* __restrict__ Br, const float* __restrict__ Bi, float* __restrict__ y2)
{
  const int t = threadIdx.x;
  const int bid = blockIdx.x;
  const int cc = bid & 3;
  const int tmp = bid >> 2;
  const int h = tmp % 14;
  const int b = tmp / 14;
  const int c = cc * 256 + t;
  const size_t ibase = (((size_t)b * CHH + h) * CKW) * CC + c;
  float br[8], bi[8];
  #pragma unroll
  for (int k = 0; k < 8; k++) {
    br[k] = Br[ibase + (size_t)k * CC];
    bi[k] = Bi[ibase + (size_t)k * CC];
  }
  const size_t obase = ((size_t)b * CN + (size_t)h * CWW) * CC + c;
  #pragma unroll
  for (int w = 0; w < 14; w++) {
    float s = br[0] + ((w & 1) ? -br[7] : br[7]);
    #pragma unroll
    for (int k = 1; k < 7; k++) {
      const int m = (w * k) % 14;
      s += 2.0f * (br[k] * C14[m] - bi[k] * S14[m]);
    }
    y2[obase + (size_t)w * CC] = s * (1.0f / 196.0f);   // ortho fwd*inv = 1/196
  }
}

// ---------------- transpose fp32 [R,Cc] -> bf16 [Cc,R] ----------------
__global__ __launch_bounds__(256)
void transpose_f32_bf16(const float* __restrict__ in, unsigned short* __restrict__ out,
                        int R, int Ccols)
{
  __shared__ float tile[32][33];
  const int tx = threadIdx.x & 31;
  const int ty = threadIdx.x >> 5;     // 0..7
  const int cb = blockIdx.x * 32;
  const int rb = blockIdx.y * 32;
  #pragma unroll
  for (int i = 0; i < 32; i += 8)
    tile[ty + i][tx] = in[(size_t)(rb + ty + i) * Ccols + cb + tx];
  __syncthreads();
  #pragma unroll
  for (int i = 0; i < 32; i += 8)
    out[(size_t)(cb + ty + i) * R + rb + tx] = f2bf(tile[tx][ty + i]);
}

// ---------------- 256x256 8-phase bf16 GEMM, 4 static LDS buffers ----------------
// C[M,N] = A[M,K] * BT[N,K]^T, +bias, optional exact GELU, bf16 out.
// 512 thr = 8 waves (2M x 4N); BK=64.
// LDS: FOUR SEPARATE static arrays A0/A1/B0/B1 (32KB each) so the backend can
// prove glds-DMA writes and ds_reads never alias (no implicit vmcnt drains).
// Depth-1 prefetch: during tile T (bufs T&1) phases stage tile T+1 into bufs
// (T+1)&1:  ph0->A-mh0, ph1->B-nh0, ph2->B-nh1, ph3->A-mh1.
// Ledger: at ph0 of T the 4 newest-but-6 loads are A-mh0(T),B-nh0(T) -> vmcnt(6);
// ph1 needs B-nh1(T) -> vmcnt(6); ph2 needs A-mh1(T) -> vmcnt(6); ph3 none.
// Last tile (no stages during it): full drain once at its ph0.
// ONE barrier per phase (post-vmcnt, pre-MFMA); skew<=1 phase keeps all
// read/write regions disjoint (stages never touch current tile's buffers).
#define STAGE(REG, TILE_, DST) do {                                           \
  const unsigned short* _g = (((REG) < 2) ? A : BT);                          \
  const int _gb = (((REG) < 2) ? brow : bcol);                                \
  int _r0, _r1;                                                               \
  if ((REG) == 0)      { _r0 = vA;       _r1 = 128 + vA; }                    \
  else if ((REG) == 1) { _r0 = 64 + vA;  _r1 = 192 + vA; }                    \
  else if ((REG) == 2) { _r0 = ((vA>>5)<<6) + (vA&31);      _r1 = _r0 + 128; }\
  else                 { _r0 = ((vA>>5)<<6) + 32 + (vA&31); _r1 = _r0 + 128; }\
  const int _gc = (TILE_) * 64 + cl;                                          \
  gload_lds16(_g + (size_t)(_gb + _r0) * K + _gc, (DST) + _r0 * 128 + dcol16);\
  gload_lds16(_g + (size_t)(_gb + _r1) * K + _gc, (DST) + _r1 * 128 + dcol16);\
} while (0)

#define PHASE(TT, CA, CB, NA, NB, PH) do {                                    \
  if (((PH) & 1) == 0) {                                                      \
    const int mh_ = (PH) >> 1;                                                \
    _Pragma("unroll")                                                         \
    for (int mf = 0; mf < 4; ++mf) {                                          \
      const int row = wm * 128 + mh_ * 64 + mf * 16 + lrow;                   \
      const int sw = (row & 7) << 4;                                          \
      af[mf][0] = *(const bf16x8*)((CA) + row * 128 + ((0  | dq) ^ sw));      \
      af[mf][1] = *(const bf16x8*)((CA) + row * 128 + ((64 | dq) ^ sw));      \
    }                                                                         \
  }                                                                           \
  {                                                                           \
    const int nh_ = (PH) & 1;                                                 \
    _Pragma("unroll")                                                         \
    for (int nf = 0; nf < 2; ++nf) {                                          \
      const int row = wn * 64 + (nh_ * 2 + nf) * 16 + lrow;                   \
      const int sw = (row & 7) << 4;                                          \
      bfr[nf][0] = *(const bf16x8*)((CB) + row * 128 + ((0  | dq) ^ sw));     \
      bfr[nf][1] = *(const bf16x8*)((CB) + row * 128 + ((64 | dq) ^ sw));     \
    }                                                                         \
  }                                                                           \
  if ((TT) + 1 < NT) {                                                        \
    if ((PH) == 0)      STAGE(0, (TT)+1, NA);                                 \
    else if ((PH) == 1) STAGE(2, (TT)+1, NB);                                 \
    else if ((PH) == 2) STAGE(3, (TT)+1, NB);                                 \
    else                STAGE(1, (TT)+1, NA);                                 \
  }                                                                           \
  if ((PH) == 0)      { if ((TT) == NT - 1) { WAITV(0); } else { WAITV(6); } }\
  else if ((PH) == 1) { WAITV(6); }                                           \
  else if ((PH) == 2) { WAITV(6); }                                           \
  SBAR();                                                                     \
  WAITLGKM0();                                                                \
  __builtin_amdgcn_sched_barrier(0);                                          \
  __builtin_amdgcn_s_setprio(1);                                              \
  {                                                                           \
    const int mh_ = (PH) >> 1, nh_ = (PH) & 1;                                \
    _Pragma("unroll")                                                         \
    for (int ks = 0; ks < 2; ++ks)                                            \
      _Pragma("unroll")                                                       \
      for (int mf = 0; mf < 4; ++mf)                                          \
        _Pragma("unroll")                                                     \
        for (int nf = 0; nf < 2; ++nf)                                        \
          acc[mh_ * 4 + mf][nh_ * 2 + nf] = __builtin_amdgcn_mfma_f32_16x16x32_bf16( \
              af[mf][ks], bfr[nf][ks], acc[mh_ * 4 + mf][nh_ * 2 + nf], 0, 0, 0); \
  }                                                                           \
  __builtin_amdgcn_s_setprio(0);                                              \
} while (0)

#define KTILE(TT, CA, CB, NA, NB) do {                                        \
  PHASE(TT, CA, CB, NA, NB, 0); PHASE(TT, CA, CB, NA, NB, 1);                 \
  PHASE(TT, CA, CB, NA, NB, 2); PHASE(TT, CA, CB, NA, NB, 3);                 \
} while (0)

template<int DO_GELU>
__global__ __launch_bounds__(512, 2)
void gemm256(const unsigned short* __restrict__ A, const unsigned short* __restrict__ BT,
             const float* __restrict__ bias, unsigned short* __restrict__ C,
             int M, int N, int K)
{
  __shared__ __align__(16) short A0s[256 * 64];
  __shared__ __align__(16) short A1s[256 * 64];
  __shared__ __align__(16) short B0s[256 * 64];
  __shared__ __align__(16) short B1s[256 * 64];
  char* a0 = (char*)A0s; char* a1 = (char*)A1s;
  char* b0 = (char*)B0s; char* b1 = (char*)B1s;

  const int t = threadIdx.x;
  const int wid = t >> 6, lane = t & 63;
  const int wm = wid >> 2, wn = wid & 3;
  const int lrow = lane & 15, qk = lane >> 4;
  const int dq = qk << 4;

  // T1: bijective XCD swizzle (m204) + GROUP=4 along N
  const int nbx = N >> 8, nby = M >> 8;
  const int nwg = nbx * nby;
  const int orig = blockIdx.x;
  const int q8 = nwg >> 3, r8 = nwg & 7, xcd = orig & 7, lid = orig >> 3;
  const int wg = (xcd < r8 ? xcd * (q8 + 1) : r8 * (q8 + 1) + (xcd - r8) * q8) + lid;
  const int gw = 4 * nby;
  const int gid = wg / gw, rem = wg % gw;
  const int bx = gid * 4 + (rem & 3);
  const int by = rem >> 2;
  const int brow = by << 8, bcol = bx << 8;
  const int NT = K >> 6;

  // staging per-thread constants
  const int vA = t >> 3;                       // 0..63
  const int cl = ((t ^ (t >> 3)) & 7) << 3;    // inverse-swizzled element col
  const int dcol16 = (t & 7) << 4;             // byte offset within LDS row

  f32x4 acc[8][4] = {};
  bf16x8 af[4][2], bfr[2][2];

  // prologue: stage K-tile 0 into buf0, drain, publish
  STAGE(0, 0, a0); STAGE(2, 0, b0); STAGE(3, 0, b0); STAGE(1, 0, a0);
  WAITV(0);
  SBAR();

  for (int T = 0; T < NT; T += 2) {
    KTILE(T,     a0, b0, a1, b1);
    KTILE(T + 1, a1, b1, a0, b0);
  }

  // epilogue: bias (+GELU) + bf16 store
  #pragma unroll
  for (int mf = 0; mf < 8; ++mf) {
    #pragma unroll
    for (int nf = 0; nf < 4; ++nf) {
      const int ccol = bcol + wn * 64 + nf * 16 + lrow;
      const float bb = bias[ccol];
      #pragma unroll
      for (int j = 0; j < 4; ++j) {
        const int r = brow + wm * 128 + mf * 16 + qk * 4 + j;
        float v = acc[mf][nf][j] + bb;
        if (DO_GELU) v = 0.5f * v * (1.0f + erff(v * 0.70710678118654752f));
        C[(size_t)r * N + ccol] = f2bf(v);
      }
    }
  }
}

// ---------------- FEM: 3 blockwise instance-norm gates fused + residual ----------------
__device__ __forceinline__ void fem_block(unsigned short* col, int t,
                                          int h0, int nh, int w0, int nw)
{
  float s = 0.f, s2 = 0.f;
  for (int ih = 0; ih < nh; ih++)
    for (int iw = 0; iw < nw; iw++) {
      const float v = bf2f(col[((h0 + ih) * 14 + w0 + iw) * 128 + t]);
      s += v; s2 += v * v;
    }
  const float inv = 1.0f / (float)(nh * nw);
  const float m = s * inv;
  const float var = s2 * inv - m * m;
  const float r = rsqrtf(var + 1e-5f);
  for (int ih = 0; ih < nh; ih++)
    for (int iw = 0; iw < nw; iw++) {
      const int idx = ((h0 + ih) * 14 + w0 + iw) * 128 + t;
      const float v = bf2f(col[idx]);
      const float a = 1.0f / (1.0f + __expf(-(v - m) * r));
      col[idx] = f2bf(0.5f * v * (1.0f + a));
    }
}

__global__ __launch_bounds__(128)
void fem_kernel(const unsigned short* __restrict__ z, const float* __restrict__ x,
                float* __restrict__ out)
{
  __shared__ unsigned short buf[CN * 128];   // 50,176 B; thread-private columns
  const int t = threadIdx.x;
  const int b = blockIdx.x >> 3;
  const int cc = blockIdx.x & 7;
  const int c = cc * 128 + t;
  const size_t base = (size_t)b * CN * CC + c;
  #pragma unroll 4
  for (int n = 0; n < CN; n++) buf[n * 128 + t] = z[base + (size_t)n * CC];
  // s = 3: 5x5 blocks, row/col starts {0,3,6,9,12}, lens {3,3,3,3,2}
  const int st3[5] = {0, 3, 6, 9, 12};
  const int ln3[5] = {3, 3, 3, 3, 2};
  for (int i = 0; i < 5; i++)
    for (int j = 0; j < 5; j++)
      fem_block(buf, t, st3[i], ln3[i], st3[j], ln3[j]);
  // s = 7: 2x2 blocks of 7x7
  for (int i = 0; i < 2; i++)
    for (int j = 0; j < 2; j++)
      fem_block(buf, t, i * 7, 7, j * 7, 7);
  // s = 14: whole field
  fem_block(buf, t, 0, 14, 0, 14);
  #pragma unroll 4
  for (int n = 0; n < CN; n++)
    out[base + (size_t)n * CC] = x[base + (size_t)n * CC] + bf2f(buf[n * 128 + t]);
}

// ---------------- launch ----------------
extern "C" void kernel_launch(void* const* d_in, const int* in_sizes, int n_in,
                              void* d_out, int out_size, void* d_ws, size_t ws_size,
                              hipStream_t stream) {
  const float* x     = (const float*)d_in[0];
  const float* ln1_g = (const float*)d_in[1];
  const float* ln1_b = (const float*)d_in[2];
  const float* cw    = (const float*)d_in[3];
  const float* ln2_g = (const float*)d_in[4];
  const float* ln2_b = (const float*)d_in[5];
  const float* fc1_w = (const float*)d_in[6];
  const float* fc1_b = (const float*)d_in[7];
  const float* fc2_w = (const float*)d_in[8];
  const float* fc2_b = (const float*)d_in[9];
  float* out = (float*)d_out;
  char* ws = (char*)d_ws;

  // arena (total 161.5 MB); d_out doubles as fp32 scratch for y1/y2
  const size_t SZ_A = (size_t)CB * CHH * CKW * CC * 4;       // 29,360,128 B
  float* Ar = (float*)(ws);
  float* Ai = (float*)(ws + SZ_A);
  float* Br = (float*)(ws + 2 * SZ_A);
  float* Bi = (float*)(ws + 3 * SZ_A);
  unsigned short* A1   = (unsigned short*)(ws);                        // after FFT done
  unsigned short* W1T  = (unsigned short*)(ws + SZ_A);                 // [4096,1024] bf16
  unsigned short* W2T  = (unsigned short*)(ws + SZ_A + (size_t)4096 * 1024 * 2); // [1024,4096]
  unsigned short* Hmid = (unsigned short*)(ws + 2 * SZ_A);             // [12544,4096] bf16
  unsigned short* Z    = (unsigned short*)(ws);                        // [12544,1024] bf16

  // 1. LN1: x -> y1 (in d_out)
  ln_kernel<0><<<CROWS, 256, 0, stream>>>(x, ln1_g, ln1_b, out, nullptr);
  // 2. rfft along W
  fft_w_fwd<<<CB * CHH * 4, 256, 0, stream>>>(out, Ar, Ai);
  // 3. fft along H + filter + ifft along H
  fft_h_filt<<<CB * CKW * 4, 256, 0, stream>>>(Ar, Ai, cw, Br, Bi);
  // 4. irfft along W -> y2 (in d_out)
  fft_w_inv<<<CB * CHH * 4, 256, 0, stream>>>(Br, Bi, out);
  // 5. LN2 -> bf16 A1
  ln_kernel<1><<<CROWS, 256, 0, stream>>>(out, ln2_g, ln2_b, nullptr, A1);
  // 6. weight prep (FFT intermediates dead)
  transpose_f32_bf16<<<dim3(4096 / 32, 1024 / 32), 256, 0, stream>>>(fc1_w, W1T, 1024, 4096);
  transpose_f32_bf16<<<dim3(1024 / 32, 4096 / 32), 256, 0, stream>>>(fc2_w, W2T, 4096, 1024);
  // 7. GEMM1 + bias + exact GELU -> Hmid bf16 (grid 16x49=784)
  gemm256<1><<<dim3(784), 512, 0, stream>>>(A1, W1T, fc1_b, Hmid, CROWS, 4096, 1024);
  // 8. GEMM2 + bias -> Z bf16 (grid 4x49=196)
  gemm256<0><<<dim3(196), 512, 0, stream>>>(Hmid, W2T, fc2_b, Z, CROWS, 1024, 4096);
  // 9. FEM x3 fused + residual -> out
  fem_kernel<<<CB * 8, 128, 0, stream>>>(Z, x, out);
}

// Round 5
// 486.799 us; speedup vs baseline: 1.2540x; 1.0135x over previous
//
#include <hip/hip_runtime.h>

// ---------------- problem constants ----------------
constexpr int CB = 64;          // batch
constexpr int CHH = 14, CWW = 14;
constexpr int CN = 196;         // CHH*CWW
constexpr int CC = 1024;        // channels
constexpr int CROWS = CB * CN;  // 12544
constexpr int CKW = 8;          // rfft bins along W

// twiddles: cos/sin(2*pi*m/14), m=0..13
constexpr float C14[14] = {
  1.0f, 0.9009688679024191f, 0.6234898018587336f, 0.2225209339563144f,
  -0.2225209339563144f, -0.6234898018587336f, -0.9009688679024191f, -1.0f,
  -0.9009688679024191f, -0.6234898018587336f, -0.2225209339563144f,
  0.2225209339563144f, 0.6234898018587336f, 0.9009688679024191f };
constexpr float S14[14] = {
  0.0f, 0.4338837391175581f, 0.7818314824680298f, 0.9749279121818236f,
  0.9749279121818236f, 0.7818314824680298f, 0.4338837391175581f, 0.0f,
  -0.4338837391175581f, -0.7818314824680298f, -0.9749279121818236f,
  -0.9749279121818236f, -0.7818314824680298f, -0.4338837391175581f };

typedef __attribute__((ext_vector_type(8))) short bf16x8;
typedef __attribute__((ext_vector_type(4))) float f32x4;

__device__ __forceinline__ unsigned short f2bf(float f) {
  unsigned u = __builtin_bit_cast(unsigned, f);
  u += 0x7FFFu + ((u >> 16) & 1u);   // RNE
  return (unsigned short)(u >> 16);
}
__device__ __forceinline__ float bf2f(unsigned short h) {
  return __builtin_bit_cast(float, (unsigned)h << 16);
}

__device__ __forceinline__ void gload_lds16(const void* g, void* l) {
  __builtin_amdgcn_global_load_lds(
      (const __attribute__((address_space(1))) void*)g,
      (__attribute__((address_space(3))) void*)l, 16, 0, 0);
}

#define WAITV(N)  asm volatile("s_waitcnt vmcnt(" #N ")" ::: "memory")
#define SBAR()    asm volatile("s_barrier" ::: "memory")
#define WAITLGKM0() asm volatile("s_waitcnt lgkmcnt(0)" ::: "memory")

// ---------------- LayerNorm over C=1024 (one block per row) ----------------
template<int OUTBF>
__global__ __launch_bounds__(256)
void ln_kernel(const float* __restrict__ in, const float* __restrict__ gam,
               const float* __restrict__ bet, float* __restrict__ outf,
               unsigned short* __restrict__ outb)
{
  const int row = blockIdx.x;
  const int t = threadIdx.x;
  const float4 v = *(const float4*)(in + (size_t)row * CC + t * 4);
  float s  = v.x + v.y + v.z + v.w;
  float s2 = v.x*v.x + v.y*v.y + v.z*v.z + v.w*v.w;
  #pragma unroll
  for (int o = 32; o > 0; o >>= 1) { s += __shfl_down(s, o); s2 += __shfl_down(s2, o); }
  __shared__ float red[8];
  const int wid = t >> 6, lane = t & 63;
  if (lane == 0) { red[wid] = s; red[4 + wid] = s2; }
  __syncthreads();
  s  = red[0] + red[1] + red[2] + red[3];
  s2 = red[4] + red[5] + red[6] + red[7];
  const float mean = s * (1.0f / CC);
  const float var  = s2 * (1.0f / CC) - mean * mean;
  const float r = rsqrtf(var + 1e-5f);
  const float4 g4 = *(const float4*)(gam + t * 4);
  const float4 b4 = *(const float4*)(bet + t * 4);
  const float o0 = (v.x - mean) * r * g4.x + b4.x;
  const float o1 = (v.y - mean) * r * g4.y + b4.y;
  const float o2 = (v.z - mean) * r * g4.z + b4.z;
  const float o3 = (v.w - mean) * r * g4.w + b4.w;
  if (OUTBF) {
    ushort4 p; p.x = f2bf(o0); p.y = f2bf(o1); p.z = f2bf(o2); p.w = f2bf(o3);
    *(ushort4*)(outb + (size_t)row * CC + t * 4) = p;
  } else {
    *(float4*)(outf + (size_t)row * CC + t * 4) = make_float4(o0, o1, o2, o3);
  }
}

// ---------------- rfft along W: [B,H,W,C] real -> [B,H,8,C] complex ----------------
__global__ __launch_bounds__(256)
void fft_w_fwd(const float* __restrict__ y, float* __restrict__ Ar, float* __restrict__ Ai)
{
  const int t = threadIdx.x;
  const int bid = blockIdx.x;      // ((b*14)+h)*4 + cc
  const int cc = bid & 3;
  const int tmp = bid >> 2;
  const int h = tmp % 14;
  const int b = tmp / 14;
  const int c = cc * 256 + t;
  const size_t base = ((size_t)b * CN + (size_t)h * CWW) * CC + c;
  float v[14];
  #pragma unroll
  for (int w = 0; w < 14; w++) v[w] = y[base + (size_t)w * CC];
  const size_t obase = (((size_t)b * CHH + h) * CKW) * CC + c;
  #pragma unroll
  for (int kw = 0; kw < 8; kw++) {
    float sr = 0.f, si = 0.f;
    #pragma unroll
    for (int w = 0; w < 14; w++) {
      const int m = (w * kw) % 14;
      sr += v[w] * C14[m];
      si -= v[w] * S14[m];
    }
    Ar[obase + (size_t)kw * CC] = sr;
    Ai[obase + (size_t)kw * CC] = si;
  }
}

// ---------------- fft along H + complex filter + ifft along H ----------------
__global__ __launch_bounds__(256)
void fft_h_filt(const float* __restrict__ Ar, const float* __restrict__ Ai,
                const float* __restrict__ cw, float* __restrict__ Br, float* __restrict__ Bi)
{
  const int t = threadIdx.x;
  const int bid = blockIdx.x;      // ((b*8)+kw)*4 + cc
  const int cc = bid & 3;
  const int tmp = bid >> 2;
  const int kw = tmp & 7;
  const int b = tmp >> 3;
  const int c = cc * 256 + t;
  const size_t base = (((size_t)b * CHH) * CKW + kw) * CC + c;   // h stride = CKW*CC
  float ar[14], ai[14];
  #pragma unroll
  for (int h = 0; h < 14; h++) {
    ar[h] = Ar[base + (size_t)h * (CKW * CC)];
    ai[h] = Ai[base + (size_t)h * (CKW * CC)];
  }
  float fr[14], fi[14];
  #pragma unroll
  for (int kh = 0; kh < 14; kh++) {
    float yr = 0.f, yi = 0.f;
    #pragma unroll
    for (int h = 0; h < 14; h++) {
      const int m = (h * kh) % 14;
      yr += ar[h] * C14[m] + ai[h] * S14[m];
      yi += ai[h] * C14[m] - ar[h] * S14[m];
    }
    const size_t widx = (((size_t)kh * CKW + kw) * CC + c) * 2;
    const float wr = cw[widx], wi = cw[widx + 1];
    fr[kh] = yr * wr - yi * wi;
    fi[kh] = yr * wi + yi * wr;
  }
  #pragma unroll
  for (int h = 0; h < 14; h++) {
    float sr = 0.f, si = 0.f;
    #pragma unroll
    for (int kh = 0; kh < 14; kh++) {
      const int m = (h * kh) % 14;
      sr += fr[kh] * C14[m] - fi[kh] * S14[m];
      si += fr[kh] * S14[m] + fi[kh] * C14[m];
    }
    Br[base + (size_t)h * (CKW * CC)] = sr;
    Bi[base + (size_t)h * (CKW * CC)] = si;
  }
}

// ---------------- irfft along W (c2r: imag of DC/Nyquist ignored) ----------------
__global__ __launch_bounds__(256)
void fft_w_inv(const float* __restrict__ Br, const float* __restrict__ Bi, float* __restrict__ y2)
{
  const int t = threadIdx.x;
  const int bid = blockIdx.x;
  const int cc = bid & 3;
  const int tmp = bid >> 2;
  const int h = tmp % 14;
  const int b = tmp / 14;
  const int c = cc * 256 + t;
  const size_t ibase = (((size_t)b * CHH + h) * CKW) * CC + c;
  float br[8], bi[8];
  #pragma unroll
  for (int k = 0; k < 8; k++) {
    br[k] = Br[ibase + (size_t)k * CC];
    bi[k] = Bi[ibase + (size_t)k * CC];
  }
  const size_t obase = ((size_t)b * CN + (size_t)h * CWW) * CC + c;
  #pragma unroll
  for (int w = 0; w < 14; w++) {
    float s = br[0] + ((w & 1) ? -br[7] : br[7]);
    #pragma unroll
    for (int k = 1; k < 7; k++) {
      const int m = (w * k) % 14;
      s += 2.0f * (br[k] * C14[m] - bi[k] * S14[m]);
    }
    y2[obase + (size_t)w * CC] = s * (1.0f / 196.0f);   // ortho fwd*inv = 1/196
  }
}

// ---------------- transpose fp32 [R,Cc] -> bf16 [Cc,R] ----------------
__global__ __launch_bounds__(256)
void transpose_f32_bf16(const float* __restrict__ in, unsigned short* __restrict__ out,
                        int R, int Ccols)
{
  __shared__ float tile[32][33];
  const int tx = threadIdx.x & 31;
  const int ty = threadIdx.x >> 5;     // 0..7
  const int cb = blockIdx.x * 32;
  const int rb = blockIdx.y * 32;
  #pragma unroll
  for (int i = 0; i < 32; i += 8)
    tile[ty + i][tx] = in[(size_t)(rb + ty + i) * Ccols + cb + tx];
  __syncthreads();
  #pragma unroll
  for (int i = 0; i < 32; i += 8)
    out[(size_t)(cb + ty + i) * R + rb + tx] = f2bf(tile[tx][ty + i]);
}

// ---------------- 256x256 bf16 GEMM, free-run K-tile, 1 barrier/tile ----------------
// C[M,N] = A[M,K] * BT[N,K]^T, +bias, optional exact GELU, bf16 out.
// 512 thr = 8 waves (2M x 4N); BK=64. LDS: 4 disjoint 32KB arrays (A0/A1/B0/B1).
// Per K-tile T (read buf[T&1], stage T+1 into buf[(T+1)&1] -> disjoint, so NO
// intra-tile barriers needed): vmcnt(0)+s_barrier at entry (staged loads have a
// full tile of slack); then per wave free-running:
//   reads A-mh0(8) + B-nh0(4) + B-nh1(4); stage 8; lgkm(0);
//   MFMA mh0 x {nh0,nh1} (32, B held in regs -> no B re-read);
//   reads A-mh1(8); lgkm(0); MFMA mh1 x {nh0,nh1} (32).
// Waves de-phase within the tile -> LDS + MFMA pipes continuously fed.
#define STAGE(REG, TILE_, DST) do {                                           \
  const unsigned short* _g = (((REG) < 2) ? A : BT);                          \
  const int _gb = (((REG) < 2) ? brow : bcol);                                \
  int _r0, _r1;                                                               \
  if ((REG) == 0)      { _r0 = vA;       _r1 = 128 + vA; }                    \
  else if ((REG) == 1) { _r0 = 64 + vA;  _r1 = 192 + vA; }                    \
  else if ((REG) == 2) { _r0 = ((vA>>5)<<6) + (vA&31);      _r1 = _r0 + 128; }\
  else                 { _r0 = ((vA>>5)<<6) + 32 + (vA&31); _r1 = _r0 + 128; }\
  const int _gc = (TILE_) * 64 + cl;                                          \
  gload_lds16(_g + (size_t)(_gb + _r0) * K + _gc, (DST) + _r0 * 128 + dcol16);\
  gload_lds16(_g + (size_t)(_gb + _r1) * K + _gc, (DST) + _r1 * 128 + dcol16);\
} while (0)

#define LOADA(CAarr, MH) do {                                                 \
  _Pragma("unroll")                                                           \
  for (int mf = 0; mf < 4; ++mf) {                                            \
    const int row = wm * 128 + (MH) * 64 + mf * 16 + lrow;                    \
    const int sw = (row & 7) << 4;                                            \
    af[mf][0] = *(const bf16x8*)((CAarr) + row * 128 + ((0  | dq) ^ sw));     \
    af[mf][1] = *(const bf16x8*)((CAarr) + row * 128 + ((64 | dq) ^ sw));     \
  }                                                                           \
} while (0)

#define LOADB(CBarr, DEST, NH) do {                                           \
  _Pragma("unroll")                                                           \
  for (int nf = 0; nf < 2; ++nf) {                                            \
    const int row = wn * 64 + ((NH) * 2 + nf) * 16 + lrow;                    \
    const int sw = (row & 7) << 4;                                            \
    DEST[nf][0] = *(const bf16x8*)((CBarr) + row * 128 + ((0  | dq) ^ sw));   \
    DEST[nf][1] = *(const bf16x8*)((CBarr) + row * 128 + ((64 | dq) ^ sw));   \
  }                                                                           \
} while (0)

#define MFMA8(MH, NH, BFR) do {                                               \
  _Pragma("unroll")                                                           \
  for (int ks = 0; ks < 2; ++ks)                                              \
    _Pragma("unroll")                                                         \
    for (int mf = 0; mf < 4; ++mf)                                            \
      _Pragma("unroll")                                                       \
      for (int nf = 0; nf < 2; ++nf)                                          \
        acc[(MH) * 4 + mf][(NH) * 2 + nf] = __builtin_amdgcn_mfma_f32_16x16x32_bf16( \
            af[mf][ks], BFR[nf][ks], acc[(MH) * 4 + mf][(NH) * 2 + nf], 0, 0, 0); \
} while (0)

#define TILEBODY(TT, CAarr, CBarr, NAarr, NBarr) do {                         \
  WAITV(0);                                                                   \
  SBAR();                                                                     \
  LOADA(CAarr, 0);                                                            \
  LOADB(CBarr, bf0, 0);                                                       \
  LOADB(CBarr, bf1, 1);                                                       \
  if ((TT) + 1 < NT) {                                                        \
    STAGE(0, (TT)+1, NAarr);                                                  \
    STAGE(2, (TT)+1, NBarr);                                                  \
    STAGE(3, (TT)+1, NBarr);                                                  \
    STAGE(1, (TT)+1, NAarr);                                                  \
  }                                                                           \
  WAITLGKM0();                                                                \
  __builtin_amdgcn_sched_barrier(0);                                          \
  __builtin_amdgcn_s_setprio(1);                                              \
  MFMA8(0, 0, bf0);                                                           \
  MFMA8(0, 1, bf1);                                                           \
  __builtin_amdgcn_s_setprio(0);                                              \
  LOADA(CAarr, 1);                                                            \
  WAITLGKM0();                                                                \
  __builtin_amdgcn_sched_barrier(0);                                          \
  __builtin_amdgcn_s_setprio(1);                                              \
  MFMA8(1, 0, bf0);                                                           \
  MFMA8(1, 1, bf1);                                                           \
  __builtin_amdgcn_s_setprio(0);                                              \
} while (0)

template<int DO_GELU>
__global__ __launch_bounds__(512, 2)
void gemm256(const unsigned short* __restrict__ A, const unsigned short* __restrict__ BT,
             const float* __restrict__ bias, unsigned short* __restrict__ C,
             int M, int N, int K)
{
  __shared__ __align__(16) short A0s[256 * 64];
  __shared__ __align__(16) short A1s[256 * 64];
  __shared__ __align__(16) short B0s[256 * 64];
  __shared__ __align__(16) short B1s[256 * 64];
  char* a0 = (char*)A0s; char* a1 = (char*)A1s;
  char* b0 = (char*)B0s; char* b1 = (char*)B1s;

  const int t = threadIdx.x;
  const int wid = t >> 6, lane = t & 63;
  const int wm = wid >> 2, wn = wid & 3;
  const int lrow = lane & 15, qk = lane >> 4;
  const int dq = qk << 4;

  // T1: bijective XCD swizzle (m204) + GROUP=4 along N
  const int nbx = N >> 8, nby = M >> 8;
  const int nwg = nbx * nby;
  const int orig = blockIdx.x;
  const int q8 = nwg >> 3, r8 = nwg & 7, xcd = orig & 7, lid = orig >> 3;
  const int wg = (xcd < r8 ? xcd * (q8 + 1) : r8 * (q8 + 1) + (xcd - r8) * q8) + lid;
  const int gw = 4 * nby;
  const int gid = wg / gw, rem = wg % gw;
  const int bx = gid * 4 + (rem & 3);
  const int by = rem >> 2;
  const int brow = by << 8, bcol = bx << 8;
  const int NT = K >> 6;

  // staging per-thread constants
  const int vA = t >> 3;                       // 0..63
  const int cl = ((t ^ (t >> 3)) & 7) << 3;    // inverse-swizzled element col
  const int dcol16 = (t & 7) << 4;             // byte offset within LDS row

  f32x4 acc[8][4] = {};
  bf16x8 af[4][2], bf0[2][2], bf1[2][2];

  // prologue: stage K-tile 0 into buf0 (tile-0's vmcnt(0) at loop entry syncs it)
  STAGE(0, 0, a0); STAGE(2, 0, b0); STAGE(3, 0, b0); STAGE(1, 0, a0);

  for (int T = 0; T < NT; T += 2) {
    TILEBODY(T,     a0, b0, a1, b1);
    TILEBODY(T + 1, a1, b1, a0, b0);
  }

  // epilogue: bias (+GELU) + bf16 store
  #pragma unroll
  for (int mf = 0; mf < 8; ++mf) {
    #pragma unroll
    for (int nf = 0; nf < 4; ++nf) {
      const int ccol = bcol + wn * 64 + nf * 16 + lrow;
      const float bb = bias[ccol];
      #pragma unroll
      for (int j = 0; j < 4; ++j) {
        const int r = brow + wm * 128 + mf * 16 + qk * 4 + j;
        float v = acc[mf][nf][j] + bb;
        if (DO_GELU) v = 0.5f * v * (1.0f + erff(v * 0.70710678118654752f));
        C[(size_t)r * N + ccol] = f2bf(v);
      }
    }
  }
}

// ---------------- FEM: 3 blockwise instance-norm gates fused + residual ----------------
__device__ __forceinline__ void fem_block(unsigned short* col, int t,
                                          int h0, int nh, int w0, int nw)
{
  float s = 0.f, s2 = 0.f;
  for (int ih = 0; ih < nh; ih++)
    for (int iw = 0; iw < nw; iw++) {
      const float v = bf2f(col[((h0 + ih) * 14 + w0 + iw) * 128 + t]);
      s += v; s2 += v * v;
    }
  const float inv = 1.0f / (float)(nh * nw);
  const float m = s * inv;
  const float var = s2 * inv - m * m;
  const float r = rsqrtf(var + 1e-5f);
  for (int ih = 0; ih < nh; ih++)
    for (int iw = 0; iw < nw; iw++) {
      const int idx = ((h0 + ih) * 14 + w0 + iw) * 128 + t;
      const float v = bf2f(col[idx]);
      const float a = 1.0f / (1.0f + __expf(-(v - m) * r));
      col[idx] = f2bf(0.5f * v * (1.0f + a));
    }
}

__global__ __launch_bounds__(128)
void fem_kernel(const unsigned short* __restrict__ z, const float* __restrict__ x,
                float* __restrict__ out)
{
  __shared__ unsigned short buf[CN * 128];   // 50,176 B; thread-private columns
  const int t = threadIdx.x;
  const int b = blockIdx.x >> 3;
  const int cc = blockIdx.x & 7;
  const int c = cc * 128 + t;
  const size_t base = (size_t)b * CN * CC + c;
  #pragma unroll 4
  for (int n = 0; n < CN; n++) buf[n * 128 + t] = z[base + (size_t)n * CC];
  // s = 3: 5x5 blocks, row/col starts {0,3,6,9,12}, lens {3,3,3,3,2}
  const int st3[5] = {0, 3, 6, 9, 12};
  const int ln3[5] = {3, 3, 3, 3, 2};
  for (int i = 0; i < 5; i++)
    for (int j = 0; j < 5; j++)
      fem_block(buf, t, st3[i], ln3[i], st3[j], ln3[j]);
  // s = 7: 2x2 blocks of 7x7
  for (int i = 0; i < 2; i++)
    for (int j = 0; j < 2; j++)
      fem_block(buf, t, i * 7, 7, j * 7, 7);
  // s = 14: whole field
  fem_block(buf, t, 0, 14, 0, 14);
  #pragma unroll 4
  for (int n = 0; n < CN; n++)
    out[base + (size_t)n * CC] = x[base + (size_t)n * CC] + bf2f(buf[n * 128 + t]);
}

// ---------------- launch ----------------
extern "C" void kernel_launch(void* const* d_in, const int* in_sizes, int n_in,
                              void* d_out, int out_size, void* d_ws, size_t ws_size,
                              hipStream_t stream) {
  const float* x     = (const float*)d_in[0];
  const float* ln1_g = (const float*)d_in[1];
  const float* ln1_b = (const float*)d_in[2];
  const float* cw    = (const float*)d_in[3];
  const float* ln2_g = (const float*)d_in[4];
  const float* ln2_b = (const float*)d_in[5];
  const float* fc1_w = (const float*)d_in[6];
  const float* fc1_b = (const float*)d_in[7];
  const float* fc2_w = (const float*)d_in[8];
  const float* fc2_b = (const float*)d_in[9];
  float* out = (float*)d_out;
  char* ws = (char*)d_ws;

  // arena (total 161.5 MB); d_out doubles as fp32 scratch for y1/y2
  const size_t SZ_A = (size_t)CB * CHH * CKW * CC * 4;       // 29,360,128 B
  float* Ar = (float*)(ws);
  float* Ai = (float*)(ws + SZ_A);
  float* Br = (float*)(ws + 2 * SZ_A);
  float* Bi = (float*)(ws + 3 * SZ_A);
  unsigned short* A1   = (unsigned short*)(ws);                        // after FFT done
  unsigned short* W1T  = (unsigned short*)(ws + SZ_A);                 // [4096,1024] bf16
  unsigned short* W2T  = (unsigned short*)(ws + SZ_A + (size_t)4096 * 1024 * 2); // [1024,4096]
  unsigned short* Hmid = (unsigned short*)(ws + 2 * SZ_A);             // [12544,4096] bf16
  unsigned short* Z    = (unsigned short*)(ws);                        // [12544,1024] bf16

  // 1. LN1: x -> y1 (in d_out)
  ln_kernel<0><<<CROWS, 256, 0, stream>>>(x, ln1_g, ln1_b, out, nullptr);
  // 2. rfft along W
  fft_w_fwd<<<CB * CHH * 4, 256, 0, stream>>>(out, Ar, Ai);
  // 3. fft along H + filter + ifft along H
  fft_h_filt<<<CB * CKW * 4, 256, 0, stream>>>(Ar, Ai, cw, Br, Bi);
  // 4. irfft along W -> y2 (in d_out)
  fft_w_inv<<<CB * CHH * 4, 256, 0, stream>>>(Br, Bi, out);
  // 5. LN2 -> bf16 A1
  ln_kernel<1><<<CROWS, 256, 0, stream>>>(out, ln2_g, ln2_b, nullptr, A1);
  // 6. weight prep (FFT intermediates dead)
  transpose_f32_bf16<<<dim3(4096 / 32, 1024 / 32), 256, 0, stream>>>(fc1_w, W1T, 1024, 4096);
  transpose_f32_bf16<<<dim3(1024 / 32, 4096 / 32), 256, 0, stream>>>(fc2_w, W2T, 4096, 1024);
  // 7. GEMM1 + bias + exact GELU -> Hmid bf16 (grid 16x49=784)
  gemm256<1><<<dim3(784), 512, 0, stream>>>(A1, W1T, fc1_b, Hmid, CROWS, 4096, 1024);
  // 8. GEMM2 + bias -> Z bf16 (grid 4x49=196)
  gemm256<0><<<dim3(196), 512, 0, stream>>>(Hmid, W2T, fc2_b, Z, CROWS, 1024, 4096);
  // 9. FEM x3 fused + residual -> out
  fem_kernel<<<CB * 8, 128, 0, stream>>>(Z, x, out);
}